// Round 3
// baseline (21123.256 us; speedup 1.0000x reference)
//
#include <hip/hip_runtime.h>
#include <hip/hip_bf16.h>
#include <hip/hip_cooperative_groups.h>

typedef __hip_bfloat16 bf16;
namespace cgn = cooperative_groups;

#define NB 16
#define PLANE (256*256)
#define CG_ITERS 100

static __device__ __forceinline__ float ldf(const float* p){ return *p; }
static __device__ __forceinline__ float ldf(const bf16* p){ return __bfloat162float(*p); }
static __device__ __forceinline__ void stf(float* p, float v){ *p = v; }
static __device__ __forceinline__ void stf(bf16* p, float v){ *p = __float2bfloat16(v); }

// ---------------- conv 3x3 SAME, NCHW, OIHW weights ----------------
template<int CIN, int SPLIT, int COUT, bool RELU, typename TIN, typename TOUT>
__global__ __launch_bounds__(256)
void conv3x3(const TIN* __restrict__ in, const TIN* __restrict__ in2,
             const float* __restrict__ wgt, const float* __restrict__ bias,
             TOUT* __restrict__ out)
{
    __shared__ TIN  s_in[CIN][18][18];
    __shared__ float s_w[CIN*9*COUT];
    const int n  = blockIdx.z;
    const int ty0 = blockIdx.y * 16, tx0 = blockIdx.x * 16;
    const int tid = threadIdx.x;

    for (int idx = tid; idx < CIN*9*COUT; idx += 256) {
        int co = idx % COUT; int rest = idx / COUT;   // rest = ci*9 + k
        s_w[idx] = wgt[(co*CIN + rest/9)*9 + rest%9];
    }
    for (int idx = tid; idx < CIN*18*18; idx += 256) {
        int ci = idx / (18*18); int rr = idx % (18*18);
        int yy = rr / 18, xx = rr % 18;
        int y = ty0 + yy - 1, x = tx0 + xx - 1;
        float v = 0.f;
        if (y >= 0 && y < 256 && x >= 0 && x < 256) {
            if (ci < SPLIT) v = ldf(&in [((size_t)(n*SPLIT + ci)*256 + y)*256 + x]);
            else            v = ldf(&in2[((size_t)(n*(CIN-SPLIT) + (ci-SPLIT))*256 + y)*256 + x]);
        }
        stf(&s_in[ci][yy][xx], v);
    }
    __syncthreads();

    const int ty = tid >> 4, tx = tid & 15;
    float acc[COUT];
    #pragma unroll
    for (int co = 0; co < COUT; co++) acc[co] = bias[co];

    for (int ci = 0; ci < CIN; ci++) {
        #pragma unroll
        for (int ky = 0; ky < 3; ky++)
        #pragma unroll
        for (int kx = 0; kx < 3; kx++) {
            float v = ldf(&s_in[ci][ty+ky][tx+kx]);
            const float* wp = &s_w[(ci*9 + ky*3 + kx)*COUT];
            #pragma unroll
            for (int co = 0; co < COUT; co++) acc[co] = fmaf(v, wp[co], acc[co]);
        }
    }
    const int y = ty0 + ty, x = tx0 + tx;
    #pragma unroll
    for (int co = 0; co < COUT; co++) {
        float v = acc[co];
        if (RELU) v = fmaxf(v, 0.f);
        stf(&out[((size_t)(n*COUT + co)*256 + y)*256 + x], v);
    }
}

// ---------------- squared neighbor differences, summed over 32 channels ----------------
template<bool ACCUM>
__global__ __launch_bounds__(256)
void dvdh_kernel(const bf16* __restrict__ f, float* __restrict__ dv, float* __restrict__ dh)
{
    int bid = blockIdx.x;
    int n = bid >> 8, i = bid & 255, j = threadIdx.x;
    const bf16* base = f + ((size_t)n*32)*PLANE + i*256 + j;
    float adv = 0.f, adh = 0.f;
    #pragma unroll 4
    for (int c = 0; c < 32; c++) {
        const bf16* pc = base + (size_t)c*PLANE;
        float fc = __bfloat162float(pc[0]);
        float fr = (j < 255) ? __bfloat162float(pc[1])   : fc;
        float fd = (i < 255) ? __bfloat162float(pc[256]) : fc;
        adh += (fr-fc)*(fr-fc);
        adv += (fd-fc)*(fd-fc);
    }
    int o = (n*256 + i)*256 + j;
    if (ACCUM) { dv[o] += adv; dh[o] += adh; }
    else       { dv[o]  = adv; dh[o]  = adh; }
}

// ---------------- affinity: compact wv/wh (for CG) + 5-plane output ----------------
__global__ __launch_bounds__(256)
void aff2_kernel(const float* __restrict__ dv, const float* __restrict__ dh,
                 const float* __restrict__ llam, const float* __restrict__ lmu,
                 float* __restrict__ wv, float* __restrict__ wh,
                 float* __restrict__ aff)
{
    int bid = blockIdx.x;
    int n = bid >> 8, h = bid & 255, w = threadIdx.x;
    float mu = expf(lmu[0]), lam = expf(llam[0]);
    int rb = (n*256 + h)*256 + w;
    float wvv = (h < 255) ? expf(-mu * dv[rb]) : 0.f;
    float whv = (w < 255) ? expf(-mu * dh[rb]) : 0.f;
    wv[rb] = wvv; wh[rb] = whv;
    float w_up = (h > 0) ? expf(-mu * dv[rb - 256]) : 0.f;
    float w_lf = (w > 0) ? expf(-mu * dh[rb - 1])   : 0.f;
    float ctr  = w_up + wvv + w_lf + whv + lam;
    float* a = aff + ((size_t)n*5)*PLANE + h*256 + w;
    a[0]        = w_up;
    a[PLANE]    = wvv;
    a[2*PLANE]  = w_lf;
    a[3*PLANE]  = whv;
    a[4*PLANE]  = ctr;
}

// ---------------- RHS (fallback path) ----------------
__global__ __launch_bounds__(256)
void brhs_kernel(const float* __restrict__ src, const float* __restrict__ mask,
                 const float* __restrict__ llam, float* __restrict__ b)
{
    int gid = blockIdx.x*256 + threadIdx.x;
    int n = gid >> 16, rem = gid & 65535, h = rem >> 8, w = rem & 255;
    float lam = expf(llam[0]);
    int bi = n*1024 + (h>>3)*32 + (w>>3);
    b[gid] = lam * mask[bi] * src[bi] * (1.f/64.f);
}

__global__ __launch_bounds__(64)
void bsum_kernel(const float* __restrict__ v, float* __restrict__ bs)
{
    int bid = blockIdx.x;                  // n*1024 + by*32 + bx
    int n = bid >> 10, by = (bid >> 5) & 31, bx = bid & 31;
    int t = threadIdx.x, dy = t >> 3, dx = t & 7;
    float val = v[((size_t)n*256 + by*8 + dy)*256 + bx*8 + dx];
    #pragma unroll
    for (int o = 32; o > 0; o >>= 1) val += __shfl_down(val, o, 64);
    if (t == 0) bs[bid] = val;
}

// ---------------- shared pieces ----------------
static __device__ __forceinline__ float cg_A(const float* __restrict__ wv,
    const float* __restrict__ wh, const float* __restrict__ y,
    int h, int w, int idx)
{
    float wvu = (h > 0) ? wv[idx-256] : 0.f;
    float wvd = wv[idx];                       // 0 at h==255 by construction
    float whl = (w > 0) ? wh[idx-1] : 0.f;
    float whr = wh[idx];                       // 0 at w==255 by construction
    float s = 0.f;
    if (h > 0)   s = fmaf(wvu, y[idx-256], s);
    if (h < 255) s = fmaf(wvd, y[idx+256], s);
    if (w > 0)   s = fmaf(whl, y[idx-1],   s);
    if (w < 255) s = fmaf(whr, y[idx+1],   s);
    float deg = wvu + wvd + whl + whr;
    return deg * y[idx] - s;
}

static __device__ __forceinline__ void block_reduce_atomic(float v, float* dst, float* sh)
{
    #pragma unroll
    for (int o = 32; o > 0; o >>= 1) v += __shfl_down(v, o, 64);
    __syncthreads();                     // protect sh reuse
    if ((threadIdx.x & 63) == 0) sh[threadIdx.x >> 6] = v;
    __syncthreads();
    if (threadIdx.x == 0) atomicAdd(dst, sh[0]+sh[1]+sh[2]+sh[3]);
}

// ---------------- cooperative CG: 512 blocks x 256 thr, 8 px/thread ----------------
// Block owns a 64x32 tile: n = b>>5, t = b&31, tyo=(t>>3)*64, txo=(t&7)*32.
// Thread (tx=tid&31, tyb=tid>>5) owns rows tyo+tyb+8i (i=0..7), col txo+tx.
// 8x8 avgpool blocks nest inside the tile -> bsum lives in LDS (s_bs[32]).
static __device__ __forceinline__ void tile_bsum8(const float v[8], int tyb, int tx,
    float* s_v /*2048*/, float* s_part /*256*/, float* s_bs /*32*/)
{
    __syncthreads();                     // protect s_v/s_bs reuse across phases
    #pragma unroll
    for (int i = 0; i < 8; i++) s_v[(tyb + 8*i)*32 + tx] = v[i];
    __syncthreads();
    int tid = threadIdx.x;
    {   // 256 row-segments of 8: blk = tid>>3 (0..31), rib = tid&7
        int blk = tid >> 3, rib = tid & 7;
        const float* r = s_v + ((blk >> 2)*8 + rib)*32 + (blk & 3)*8;
        s_part[tid] = r[0]+r[1]+r[2]+r[3]+r[4]+r[5]+r[6]+r[7];
    }
    __syncthreads();
    if (tid < 32) {
        const float* q = s_part + tid*8;
        s_bs[tid] = q[0]+q[1]+q[2]+q[3]+q[4]+q[5]+q[6]+q[7];
    }
    // caller's grid.sync() (includes block barrier) makes s_bs visible
}

__global__ __launch_bounds__(256, 3)
void cg_coop(const float* __restrict__ wv, const float* __restrict__ wh,
             const float* __restrict__ mask, const float* __restrict__ src,
             const float* __restrict__ ybic, const float* __restrict__ llam,
             float* __restrict__ p, float* __restrict__ scal,
             float* __restrict__ x_out)
{
    __shared__ float s_v[2048], s_part[256], s_bs[32], s_sh[4];
    cgn::grid_group grid = cgn::this_grid();

    const int tid = threadIdx.x;
    const int b = blockIdx.x;
    const int n = b >> 5, t = b & 31;
    const int tyo = (t >> 3) * 64, txo = (t & 7) * 32;
    const int tx = tid & 31, tyb = tid >> 5;
    const int w = txo + tx;
    const float lam = expf(llam[0]);

    const float* wvn = wv   + (size_t)n * PLANE;
    const float* whn = wh   + (size_t)n * PLANE;
    const float* ybn = ybic + (size_t)n * PLANE;
    float*       pn  = p    + (size_t)n * PLANE;

    int hh[8], idx[8], lb[8];
    float c1[8], brhs[8];
    #pragma unroll
    for (int i = 0; i < 8; i++) {
        hh[i]  = tyo + tyb + 8*i;
        idx[i] = hh[i]*256 + w;
        lb[i]  = i*4 + (tx >> 3);           // row-block i (tyb<8), col-block tx>>3
        int bi = n*1024 + (hh[i] >> 3)*32 + (w >> 3);
        float mv = mask[bi];
        c1[i]   = lam * mv * (1.f/4096.f);
        brhs[i] = lam * mv * src[bi] * (1.f/64.f);
    }
    float xv[8], rv[8], pv[8], Apv[8];

    // phase 0: bsum(ybic tile) for A*x0   (scal pre-zeroed by hipMemsetAsync)
    float yv[8];
    #pragma unroll
    for (int i = 0; i < 8; i++) { yv[i] = ybn[idx[i]]; xv[i] = yv[i]; }
    tile_bsum8(yv, tyb, tx, s_v, s_part, s_bs);
    grid.sync();

    // phase 0b: r0 = b - A*x0; p0 = r0; gamma0 = r.r; publish p; bsum(p)
    float g0 = 0.f;
    #pragma unroll
    for (int i = 0; i < 8; i++) {
        float ax = cg_A(wvn, whn, ybn, hh[i], w, idx[i]) + c1[i]*s_bs[lb[i]];
        rv[i] = brhs[i] - ax;
        pv[i] = rv[i];
        pn[idx[i]] = pv[i];
        g0 += rv[i]*rv[i];
    }
    block_reduce_atomic(g0, &scal[0], s_sh);
    tile_bsum8(pv, tyb, tx, s_v, s_part, s_bs);
    grid.sync();

    float* gamma = scal;         // [0..100]
    float* pAp   = scal + 128;   // [0..99]

    for (int k = 0; k < CG_ITERS; k++) {
        // phase 1: Ap = A*p (p halo from global, bs from LDS); pAp reduction
        float lpap = 0.f;
        #pragma unroll
        for (int i = 0; i < 8; i++) {
            Apv[i] = cg_A(wvn, whn, pn, hh[i], w, idx[i]) + c1[i]*s_bs[lb[i]];
            lpap += pv[i]*Apv[i];
        }
        block_reduce_atomic(lpap, &pAp[k], s_sh);
        grid.sync();

        // phase 2: alpha; x += alpha p; r -= alpha Ap; gamma_new reduction
        float alpha = gamma[k] / pAp[k];
        float gn = 0.f;
        #pragma unroll
        for (int i = 0; i < 8; i++) {
            xv[i] += alpha*pv[i];
            rv[i] -= alpha*Apv[i];
            gn += rv[i]*rv[i];
        }
        block_reduce_atomic(gn, &gamma[k+1], s_sh);
        grid.sync();

        // phase 3: beta; p = r + beta p; publish p + tile bsums
        float beta = gamma[k+1] / gamma[k];
        #pragma unroll
        for (int i = 0; i < 8; i++) {
            pv[i] = rv[i] + beta*pv[i];
            pn[idx[i]] = pv[i];
        }
        tile_bsum8(pv, tyb, tx, s_v, s_part, s_bs);
        grid.sync();
    }

    #pragma unroll
    for (int i = 0; i < 8; i++) x_out[(size_t)n*PLANE + idx[i]] = xv[i];
}

// ---------------- fallback CG (proven R1 path, 5-plane aff) ----------------
static __device__ __forceinline__ float cg_stencil5(const float* __restrict__ aff,
    const float* __restrict__ y, const float* __restrict__ bs,
    const float* __restrict__ mask, float lam, int n, int h, int w)
{
    const float* a  = aff + ((size_t)n*5)*PLANE + h*256 + w;
    const float* yp = y + (size_t)n*PLANE + h*256 + w;
    float s = 0.f;
    if (h > 0)   s += a[0]       * yp[-256];
    if (h < 255) s += a[PLANE]   * yp[256];
    if (w > 0)   s += a[2*PLANE] * yp[-1];
    if (w < 255) s += a[3*PLANE] * yp[1];
    float deg = a[4*PLANE] - lam;
    int bi = n*1024 + (h>>3)*32 + (w>>3);
    return deg * yp[0] - s + lam * mask[bi] * bs[bi] * (1.f/4096.f);
}

__global__ __launch_bounds__(256)
void cg_init_kernel(const float* __restrict__ aff, const float* __restrict__ ybic,
    const float* __restrict__ bs, const float* __restrict__ mask,
    const float* __restrict__ brhs, const float* __restrict__ llam,
    float* __restrict__ x, float* __restrict__ r, float* __restrict__ p,
    float* __restrict__ gamma0)
{
    __shared__ float sh[4];
    int gid = blockIdx.x*256 + threadIdx.x;
    int n = gid >> 16, rem = gid & 65535, h = rem >> 8, w = rem & 255;
    float lam = expf(llam[0]);
    float ax = cg_stencil5(aff, ybic, bs, mask, lam, n, h, w);
    float r0 = brhs[gid] - ax;
    r[gid] = r0; p[gid] = r0; x[gid] = ybic[gid];
    block_reduce_atomic(r0*r0, gamma0, sh);
}

__global__ __launch_bounds__(256)
void cg_matvec_kernel(const float* __restrict__ aff, const float* __restrict__ p,
    const float* __restrict__ bs, const float* __restrict__ mask,
    const float* __restrict__ llam, float* __restrict__ Ap, float* __restrict__ pAp)
{
    __shared__ float sh[4];
    int gid = blockIdx.x*256 + threadIdx.x;
    int n = gid >> 16, rem = gid & 65535, h = rem >> 8, w = rem & 255;
    float lam = expf(llam[0]);
    float ap = cg_stencil5(aff, p, bs, mask, lam, n, h, w);
    Ap[gid] = ap;
    block_reduce_atomic(p[gid]*ap, pAp, sh);
}

__global__ __launch_bounds__(256)
void cg_update_kernel(float* __restrict__ x, float* __restrict__ r,
    const float* __restrict__ p, const float* __restrict__ Ap,
    const float* __restrict__ gk, const float* __restrict__ pApk,
    float* __restrict__ gk1)
{
    __shared__ float sh[4];
    int gid = blockIdx.x*256 + threadIdx.x;
    float alpha = *gk / *pApk;
    x[gid] += alpha * p[gid];
    float rn = r[gid] - alpha * Ap[gid];
    r[gid] = rn;
    block_reduce_atomic(rn*rn, gk1, sh);
}

__global__ __launch_bounds__(256)
void cg_pupdate_kernel(float* __restrict__ p, const float* __restrict__ r,
    const float* __restrict__ gk1, const float* __restrict__ gk)
{
    int gid = blockIdx.x*256 + threadIdx.x;
    float beta = *gk1 / *gk;
    p[gid] = r[gid] + beta * p[gid];
}

// ---------------- host ----------------
extern "C" void kernel_launch(void* const* d_in, const int* in_sizes, int n_in,
                              void* d_out, int out_size, void* d_ws, size_t ws_size,
                              hipStream_t stream)
{
    (void)in_sizes; (void)n_in; (void)out_size; (void)ws_size;
    const float* guide = (const float*)d_in[0];
    const float* source= (const float*)d_in[1];
    const float* mask  = (const float*)d_in[2];
    const float* ybic  = (const float*)d_in[3];
    const float* gw1 = (const float*)d_in[4];  const float* gb1 = (const float*)d_in[5];
    const float* gw2 = (const float*)d_in[6];  const float* gb2 = (const float*)d_in[7];
    const float* sw1 = (const float*)d_in[8];  const float* sb1 = (const float*)d_in[9];
    const float* sw2 = (const float*)d_in[10]; const float* sb2 = (const float*)d_in[11];
    const float* vw1 = (const float*)d_in[12]; const float* vb1 = (const float*)d_in[13];
    const float* vw2 = (const float*)d_in[14]; const float* vb2 = (const float*)d_in[15];
    const float* vw3 = (const float*)d_in[16]; const float* vb3 = (const float*)d_in[17];
    const float* llam = (const float*)d_in[18];
    const float* lmu  = (const float*)d_in[19];

    float* out     = (float*)d_out;
    float* x_out   = out;                 // y_pred (16,1,256,256)
    float* var_out = out + 1048576;       // var
    float* aff_out = out + 2097152;       // aff (16,5,256,256)

    char* ws = (char*)d_ws;
    size_t o = 0;
    bf16* bufA = (bf16*)(ws + o); o += (size_t)NB*32*PLANE*2;
    bf16* bufB = (bf16*)(ws + o); o += (size_t)NB*32*PLANE*2;
    float* dv  = (float*)(ws + o); o += (size_t)NB*PLANE*4;
    float* dh  = (float*)(ws + o); o += (size_t)NB*PLANE*4;
    float* wv  = (float*)(ws + o); o += (size_t)NB*PLANE*4;
    float* wh  = (float*)(ws + o); o += (size_t)NB*PLANE*4;
    float* pp  = (float*)(ws + o); o += (size_t)NB*PLANE*4;
    float* rr  = (float*)(ws + o); o += (size_t)NB*PLANE*4;
    float* Ap  = (float*)(ws + o); o += (size_t)NB*PLANE*4;
    float* brhs= (float*)(ws + o); o += (size_t)NB*PLANE*4;
    float* bs  = (float*)(ws + o); o += 16384*4;
    float* scal= (float*)(ws + o); o += 1024;

    dim3 cgrid(16, 16, NB);

    // feature branch g = conv(relu(conv(guide)))
    conv3x3<3,3,32,true ,float,bf16><<<cgrid,256,0,stream>>>(guide, guide, gw1, gb1, bufA);
    conv3x3<32,32,32,false,bf16,bf16><<<cgrid,256,0,stream>>>(bufA, bufA, gw2, gb2, bufB);
    dvdh_kernel<false><<<4096,256,0,stream>>>(bufB, dv, dh);
    // feature branch s = conv(relu(conv(y_bicubic)))
    conv3x3<1,1,32,true ,float,bf16><<<cgrid,256,0,stream>>>(ybic, ybic, sw1, sb1, bufA);
    conv3x3<32,32,32,false,bf16,bf16><<<cgrid,256,0,stream>>>(bufA, bufA, sw2, sb2, bufB);
    dvdh_kernel<true><<<4096,256,0,stream>>>(bufB, dv, dh);
    aff2_kernel<<<4096,256,0,stream>>>(dv, dh, llam, lmu, wv, wh, aff_out);
    // variance branch
    conv3x3<4,3,32,true ,float,bf16><<<cgrid,256,0,stream>>>(guide, ybic, vw1, vb1, bufA);
    conv3x3<32,32,32,true ,bf16,bf16><<<cgrid,256,0,stream>>>(bufA, bufA, vw2, vb2, bufB);
    conv3x3<32,32,1,false,bf16,float><<<cgrid,256,0,stream>>>(bufB, bufB, vw3, vb3, var_out);

    // zero scalar slots (capture-safe memset node)
    hipMemsetAsync(scal, 0, 1024, stream);

    // CG solve: cooperative kernel (512 blocks, headroom vs 768 capacity);
    // on launch failure, fall back to the proven multi-kernel loop.
    void* args[] = { (void*)&wv, (void*)&wh, (void*)&mask, (void*)&source,
                     (void*)&ybic, (void*)&llam, (void*)&pp, (void*)&scal,
                     (void*)&x_out };
    hipError_t err = hipLaunchCooperativeKernel((void*)cg_coop, dim3(512), dim3(256),
                                                args, 0, stream);
    if (err != hipSuccess) {
        float* gamma = scal;          // [0..100]
        float* pAp   = scal + 128;    // [0..99]
        brhs_kernel<<<4096,256,0,stream>>>(source, mask, llam, brhs);
        bsum_kernel<<<16384,64,0,stream>>>(ybic, bs);
        cg_init_kernel<<<4096,256,0,stream>>>(aff_out, ybic, bs, mask, brhs, llam,
                                              x_out, rr, pp, gamma);
        for (int k = 0; k < 100; k++) {
            bsum_kernel<<<16384,64,0,stream>>>(pp, bs);
            cg_matvec_kernel<<<4096,256,0,stream>>>(aff_out, pp, bs, mask, llam, Ap, pAp + k);
            cg_update_kernel<<<4096,256,0,stream>>>(x_out, rr, pp, Ap, gamma + k, pAp + k, gamma + k + 1);
            cg_pupdate_kernel<<<4096,256,0,stream>>>(pp, rr, gamma + k + 1, gamma + k);
        }
    }
}

// Round 4
// 6315.474 us; speedup vs baseline: 3.3447x; 3.3447x over previous
//
#include <hip/hip_runtime.h>
#include <hip/hip_bf16.h>

typedef __hip_bfloat16 bf16;

#define NB 16
#define PLANE (256*256)
#define CG_ITERS 100

static __device__ __forceinline__ float ldf(const float* p){ return *p; }
static __device__ __forceinline__ float ldf(const bf16* p){ return __bfloat162float(*p); }
static __device__ __forceinline__ void stf(float* p, float v){ *p = v; }
static __device__ __forceinline__ void stf(bf16* p, float v){ *p = __float2bfloat16(v); }

// ---------------- conv 3x3 SAME, NCHW, OIHW weights ----------------
template<int CIN, int SPLIT, int COUT, bool RELU, typename TIN, typename TOUT>
__global__ __launch_bounds__(256)
void conv3x3(const TIN* __restrict__ in, const TIN* __restrict__ in2,
             const float* __restrict__ wgt, const float* __restrict__ bias,
             TOUT* __restrict__ out)
{
    __shared__ TIN  s_in[CIN][18][18];
    __shared__ float s_w[CIN*9*COUT];
    const int n  = blockIdx.z;
    const int ty0 = blockIdx.y * 16, tx0 = blockIdx.x * 16;
    const int tid = threadIdx.x;

    for (int idx = tid; idx < CIN*9*COUT; idx += 256) {
        int co = idx % COUT; int rest = idx / COUT;   // rest = ci*9 + k
        s_w[idx] = wgt[(co*CIN + rest/9)*9 + rest%9];
    }
    for (int idx = tid; idx < CIN*18*18; idx += 256) {
        int ci = idx / (18*18); int rr = idx % (18*18);
        int yy = rr / 18, xx = rr % 18;
        int y = ty0 + yy - 1, x = tx0 + xx - 1;
        float v = 0.f;
        if (y >= 0 && y < 256 && x >= 0 && x < 256) {
            if (ci < SPLIT) v = ldf(&in [((size_t)(n*SPLIT + ci)*256 + y)*256 + x]);
            else            v = ldf(&in2[((size_t)(n*(CIN-SPLIT) + (ci-SPLIT))*256 + y)*256 + x]);
        }
        stf(&s_in[ci][yy][xx], v);
    }
    __syncthreads();

    const int ty = tid >> 4, tx = tid & 15;
    float acc[COUT];
    #pragma unroll
    for (int co = 0; co < COUT; co++) acc[co] = bias[co];

    for (int ci = 0; ci < CIN; ci++) {
        #pragma unroll
        for (int ky = 0; ky < 3; ky++)
        #pragma unroll
        for (int kx = 0; kx < 3; kx++) {
            float v = ldf(&s_in[ci][ty+ky][tx+kx]);
            const float* wp = &s_w[(ci*9 + ky*3 + kx)*COUT];
            #pragma unroll
            for (int co = 0; co < COUT; co++) acc[co] = fmaf(v, wp[co], acc[co]);
        }
    }
    const int y = ty0 + ty, x = tx0 + tx;
    #pragma unroll
    for (int co = 0; co < COUT; co++) {
        float v = acc[co];
        if (RELU) v = fmaxf(v, 0.f);
        stf(&out[((size_t)(n*COUT + co)*256 + y)*256 + x], v);
    }
}

// ---------------- squared neighbor differences, summed over 32 channels ----------------
template<bool ACCUM>
__global__ __launch_bounds__(256)
void dvdh_kernel(const bf16* __restrict__ f, float* __restrict__ dv, float* __restrict__ dh)
{
    int bid = blockIdx.x;
    int n = bid >> 8, i = bid & 255, j = threadIdx.x;
    const bf16* base = f + ((size_t)n*32)*PLANE + i*256 + j;
    float adv = 0.f, adh = 0.f;
    #pragma unroll 4
    for (int c = 0; c < 32; c++) {
        const bf16* pc = base + (size_t)c*PLANE;
        float fc = __bfloat162float(pc[0]);
        float fr = (j < 255) ? __bfloat162float(pc[1])   : fc;
        float fd = (i < 255) ? __bfloat162float(pc[256]) : fc;
        adh += (fr-fc)*(fr-fc);
        adv += (fd-fc)*(fd-fc);
    }
    int o = (n*256 + i)*256 + j;
    if (ACCUM) { dv[o] += adv; dh[o] += adh; }
    else       { dv[o]  = adv; dh[o]  = adh; }
}

// ---------------- affinity: compact wv/wh (for CG) + 5-plane output ----------------
// wv[n,h,w] = (h<255)? exp(-mu*dv) : 0 ; wh[n,h,w] = (w<255)? exp(-mu*dh) : 0
__global__ __launch_bounds__(256)
void aff2_kernel(const float* __restrict__ dv, const float* __restrict__ dh,
                 const float* __restrict__ llam, const float* __restrict__ lmu,
                 float* __restrict__ wv, float* __restrict__ wh,
                 float* __restrict__ aff)
{
    int bid = blockIdx.x;
    int n = bid >> 8, h = bid & 255, w = threadIdx.x;
    float mu = expf(lmu[0]), lam = expf(llam[0]);
    int rb = (n*256 + h)*256 + w;
    float wvv = (h < 255) ? expf(-mu * dv[rb]) : 0.f;
    float whv = (w < 255) ? expf(-mu * dh[rb]) : 0.f;
    wv[rb] = wvv; wh[rb] = whv;
    float w_up = (h > 0) ? expf(-mu * dv[rb - 256]) : 0.f;
    float w_lf = (w > 0) ? expf(-mu * dh[rb - 1])   : 0.f;
    float ctr  = w_up + wvv + w_lf + whv + lam;
    float* a = aff + ((size_t)n*5)*PLANE + h*256 + w;
    a[0]        = w_up;
    a[PLANE]    = wvv;
    a[2*PLANE]  = w_lf;
    a[3*PLANE]  = whv;
    a[4*PLANE]  = ctr;
}

// ---------------- shared reduction ----------------
static __device__ __forceinline__ void block_reduce_atomic(float v, float* dst, float* sh)
{
    #pragma unroll
    for (int o = 32; o > 0; o >>= 1) v += __shfl_down(v, o, 64);
    __syncthreads();
    if ((threadIdx.x & 63) == 0) sh[threadIdx.x >> 6] = v;
    __syncthreads();
    if (threadIdx.x == 0) atomicAdd(dst, sh[0]+sh[1]+sh[2]+sh[3]);
}

// ============ CG: 2 dispatches/iteration, tile-fused ============
// Tiles: 1024 blocks x 256 threads; block owns 32x32 (n=b>>6, t=b&63).
// Thread (tx=tid&31, tyb=tid>>5) owns rows tyo+tyb+8i, i=0..3.
// scal: gamma[k]=scal[k] (k=0..100), pAp[k]=scal[128+k].

// init: r0 = b - A*ybic ; p0 = r0 ; x = ybic ; gamma0
__global__ __launch_bounds__(256)
void cg_init(const float* __restrict__ wv, const float* __restrict__ wh,
             const float* __restrict__ mask, const float* __restrict__ src,
             const float* __restrict__ ybic, const float* __restrict__ llam,
             float* __restrict__ x, float* __restrict__ r, float* __restrict__ p0,
             float* __restrict__ scal)
{
    __shared__ float s_pn[34][35];
    __shared__ float s_part[128], s_bs[16], s_red[4];
    const int tid = threadIdx.x;
    const int b = blockIdx.x;
    const int n = b >> 6, t = b & 63;
    const int tyo = (t >> 3) * 32, txo = (t & 7) * 32;
    const int tx = tid & 31, tyb = tid >> 5;
    const int w = txo + tx;
    const float lam = expf(llam[0]);

    const float* ybn = ybic + (size_t)n*PLANE;
    float yv[4];
    #pragma unroll
    for (int i = 0; i < 4; i++) {
        int h = tyo + tyb + 8*i;
        yv[i] = ybn[h*256 + w];
        s_pn[1 + tyb + 8*i][1 + tx] = yv[i];
    }
    if (tid < 128) {
        int which = tid >> 5, lane = tid & 31;
        int y, xx;
        if      (which == 0) { y = tyo - 1;    xx = txo + lane; }
        else if (which == 1) { y = tyo + 32;   xx = txo + lane; }
        else if (which == 2) { y = tyo + lane; xx = txo - 1;    }
        else                 { y = tyo + lane; xx = txo + 32;   }
        float v = 0.f;
        if (y >= 0 && y < 256 && xx >= 0 && xx < 256) v = ybn[y*256 + xx];
        s_pn[y - tyo + 1][xx - txo + 1] = v;
    }
    __syncthreads();
    if (tid < 128) {
        int blk = tid >> 3, rib = tid & 7;
        const float* rw = &s_pn[1 + (blk>>2)*8 + rib][1 + (blk&3)*8];
        s_part[tid] = rw[0]+rw[1]+rw[2]+rw[3]+rw[4]+rw[5]+rw[6]+rw[7];
    }
    __syncthreads();
    if (tid < 16) {
        const float* q = s_part + tid*8;
        s_bs[tid] = q[0]+q[1]+q[2]+q[3]+q[4]+q[5]+q[6]+q[7];
    }
    __syncthreads();

    const float* wvn = wv + (size_t)n*PLANE;
    const float* whn = wh + (size_t)n*PLANE;
    float* rn = r  + (size_t)n*PLANE;
    float* pn = p0 + (size_t)n*PLANE;
    float* xn = x  + (size_t)n*PLANE;
    float g0 = 0.f;
    #pragma unroll
    for (int i = 0; i < 4; i++) {
        int h = tyo + tyb + 8*i;
        int idx = h*256 + w;
        int yy = 1 + tyb + 8*i, xx = 1 + tx;
        float wvu = (h > 0) ? wvn[idx-256] : 0.f;
        float wvd = wvn[idx];
        float whl = (w > 0) ? whn[idx-1] : 0.f;
        float whr = whn[idx];
        float s = wvu*s_pn[yy-1][xx] + wvd*s_pn[yy+1][xx]
                + whl*s_pn[yy][xx-1] + whr*s_pn[yy][xx+1];
        float deg = wvu+wvd+whl+whr;
        int bi = n*1024 + (h>>3)*32 + (w>>3);
        float mv = mask[bi];
        float ax = deg*s_pn[yy][xx] - s + lam*mv*(1.f/4096.f)*s_bs[i*4 + (tx>>3)];
        float brhs = lam*mv*src[bi]*(1.f/64.f);
        float r0 = brhs - ax;
        rn[idx] = r0; pn[idx] = r0; xn[idx] = yv[i];
        g0 += r0*r0;
    }
    block_reduce_atomic(g0, &scal[0], s_red);
}

// step1: beta = gamma[k]/gamma[k-1] (0 at k==0); p_new = r + beta*p_old
// (halo recomputed, so no dependence on neighbors' p_new); bs(p_new) in LDS;
// Ap = A*p_new; pAp reduction. p double-buffered.
__global__ __launch_bounds__(256)
void cg_step1(const float* __restrict__ wv, const float* __restrict__ wh,
              const float* __restrict__ mask, const float* __restrict__ llam,
              const float* __restrict__ r, const float* __restrict__ pold,
              float* __restrict__ pnew, float* __restrict__ Ap,
              float* __restrict__ scal, int k)
{
    __shared__ float s_pn[34][35];
    __shared__ float s_part[128], s_bs[16], s_red[4];
    const int tid = threadIdx.x;
    const int b = blockIdx.x;
    const int n = b >> 6, t = b & 63;
    const int tyo = (t >> 3) * 32, txo = (t & 7) * 32;
    const int tx = tid & 31, tyb = tid >> 5;
    const int w = txo + tx;
    const float lam = expf(llam[0]);
    const float beta = (k == 0) ? 0.f : scal[k] / scal[k-1];

    const float* rn = r    + (size_t)n*PLANE;
    const float* po = pold + (size_t)n*PLANE;

    float pv[4];
    #pragma unroll
    for (int i = 0; i < 4; i++) {
        int h = tyo + tyb + 8*i;
        int idx = h*256 + w;
        pv[i] = fmaf(beta, po[idx], rn[idx]);
        s_pn[1 + tyb + 8*i][1 + tx] = pv[i];
    }
    if (tid < 128) {
        int which = tid >> 5, lane = tid & 31;
        int y, xx;
        if      (which == 0) { y = tyo - 1;    xx = txo + lane; }
        else if (which == 1) { y = tyo + 32;   xx = txo + lane; }
        else if (which == 2) { y = tyo + lane; xx = txo - 1;    }
        else                 { y = tyo + lane; xx = txo + 32;   }
        float v = 0.f;
        if (y >= 0 && y < 256 && xx >= 0 && xx < 256) {
            int idx = y*256 + xx;
            v = fmaf(beta, po[idx], rn[idx]);
        }
        s_pn[y - tyo + 1][xx - txo + 1] = v;
    }
    __syncthreads();
    if (tid < 128) {
        int blk = tid >> 3, rib = tid & 7;
        const float* rw = &s_pn[1 + (blk>>2)*8 + rib][1 + (blk&3)*8];
        s_part[tid] = rw[0]+rw[1]+rw[2]+rw[3]+rw[4]+rw[5]+rw[6]+rw[7];
    }
    __syncthreads();
    if (tid < 16) {
        const float* q = s_part + tid*8;
        s_bs[tid] = q[0]+q[1]+q[2]+q[3]+q[4]+q[5]+q[6]+q[7];
    }
    __syncthreads();

    const float* wvn = wv + (size_t)n*PLANE;
    const float* whn = wh + (size_t)n*PLANE;
    float* pw  = pnew + (size_t)n*PLANE;
    float* Apn = Ap   + (size_t)n*PLANE;
    float lsum = 0.f;
    #pragma unroll
    for (int i = 0; i < 4; i++) {
        int h = tyo + tyb + 8*i;
        int idx = h*256 + w;
        int yy = 1 + tyb + 8*i, xx = 1 + tx;
        float wvu = (h > 0) ? wvn[idx-256] : 0.f;
        float wvd = wvn[idx];
        float whl = (w > 0) ? whn[idx-1] : 0.f;
        float whr = whn[idx];
        float s = wvu*s_pn[yy-1][xx] + wvd*s_pn[yy+1][xx]
                + whl*s_pn[yy][xx-1] + whr*s_pn[yy][xx+1];
        float deg = wvu+wvd+whl+whr;
        int bi = n*1024 + (h>>3)*32 + (w>>3);
        float c1 = lam*mask[bi]*(1.f/4096.f);
        float ap = deg*s_pn[yy][xx] - s + c1*s_bs[i*4 + (tx>>3)];
        Apn[idx] = ap;
        pw[idx]  = pv[i];
        lsum += pv[i]*ap;
    }
    block_reduce_atomic(lsum, &scal[128+k], s_red);
}

// step2: alpha = gamma[k]/pAp[k]; x += alpha p; r -= alpha Ap; gamma[k+1]
__global__ __launch_bounds__(256)
void cg_step2(float* __restrict__ x, float* __restrict__ r,
              const float* __restrict__ p, const float* __restrict__ Ap,
              float* __restrict__ scal, int k)
{
    __shared__ float s_red[4];
    int g = blockIdx.x*256 + threadIdx.x;       // float4 index
    float alpha = scal[k] / scal[128+k];
    float4 pv = ((const float4*)p)[g];
    float4 av = ((const float4*)Ap)[g];
    float4 xv = ((float4*)x)[g];
    float4 rv = ((float4*)r)[g];
    xv.x = fmaf(alpha, pv.x, xv.x); rv.x = fmaf(-alpha, av.x, rv.x);
    xv.y = fmaf(alpha, pv.y, xv.y); rv.y = fmaf(-alpha, av.y, rv.y);
    xv.z = fmaf(alpha, pv.z, xv.z); rv.z = fmaf(-alpha, av.z, rv.z);
    xv.w = fmaf(alpha, pv.w, xv.w); rv.w = fmaf(-alpha, av.w, rv.w);
    ((float4*)x)[g] = xv;
    ((float4*)r)[g] = rv;
    float gn = rv.x*rv.x + rv.y*rv.y + rv.z*rv.z + rv.w*rv.w;
    block_reduce_atomic(gn, &scal[k+1], s_red);
}

// ---------------- host ----------------
extern "C" void kernel_launch(void* const* d_in, const int* in_sizes, int n_in,
                              void* d_out, int out_size, void* d_ws, size_t ws_size,
                              hipStream_t stream)
{
    (void)in_sizes; (void)n_in; (void)out_size; (void)ws_size;
    const float* guide = (const float*)d_in[0];
    const float* source= (const float*)d_in[1];
    const float* mask  = (const float*)d_in[2];
    const float* ybic  = (const float*)d_in[3];
    const float* gw1 = (const float*)d_in[4];  const float* gb1 = (const float*)d_in[5];
    const float* gw2 = (const float*)d_in[6];  const float* gb2 = (const float*)d_in[7];
    const float* sw1 = (const float*)d_in[8];  const float* sb1 = (const float*)d_in[9];
    const float* sw2 = (const float*)d_in[10]; const float* sb2 = (const float*)d_in[11];
    const float* vw1 = (const float*)d_in[12]; const float* vb1 = (const float*)d_in[13];
    const float* vw2 = (const float*)d_in[14]; const float* vb2 = (const float*)d_in[15];
    const float* vw3 = (const float*)d_in[16]; const float* vb3 = (const float*)d_in[17];
    const float* llam = (const float*)d_in[18];
    const float* lmu  = (const float*)d_in[19];

    float* out     = (float*)d_out;
    float* x_out   = out;                 // y_pred (16,1,256,256)
    float* var_out = out + 1048576;       // var
    float* aff_out = out + 2097152;       // aff (16,5,256,256)

    char* ws = (char*)d_ws;
    size_t o = 0;
    bf16* bufA = (bf16*)(ws + o); o += (size_t)NB*32*PLANE*2;
    bf16* bufB = (bf16*)(ws + o); o += (size_t)NB*32*PLANE*2;
    float* dv  = (float*)(ws + o); o += (size_t)NB*PLANE*4;
    float* dh  = (float*)(ws + o); o += (size_t)NB*PLANE*4;
    float* wv  = (float*)(ws + o); o += (size_t)NB*PLANE*4;
    float* wh  = (float*)(ws + o); o += (size_t)NB*PLANE*4;
    float* pb0 = (float*)(ws + o); o += (size_t)NB*PLANE*4;
    float* pb1 = (float*)(ws + o); o += (size_t)NB*PLANE*4;
    float* rr  = (float*)(ws + o); o += (size_t)NB*PLANE*4;
    float* App = (float*)(ws + o); o += (size_t)NB*PLANE*4;
    float* scal= (float*)(ws + o); o += 1024;

    dim3 cgrid(16, 16, NB);

    // feature branch g = conv(relu(conv(guide)))
    conv3x3<3,3,32,true ,float,bf16><<<cgrid,256,0,stream>>>(guide, guide, gw1, gb1, bufA);
    conv3x3<32,32,32,false,bf16,bf16><<<cgrid,256,0,stream>>>(bufA, bufA, gw2, gb2, bufB);
    dvdh_kernel<false><<<4096,256,0,stream>>>(bufB, dv, dh);
    // feature branch s = conv(relu(conv(y_bicubic)))
    conv3x3<1,1,32,true ,float,bf16><<<cgrid,256,0,stream>>>(ybic, ybic, sw1, sb1, bufA);
    conv3x3<32,32,32,false,bf16,bf16><<<cgrid,256,0,stream>>>(bufA, bufA, sw2, sb2, bufB);
    dvdh_kernel<true><<<4096,256,0,stream>>>(bufB, dv, dh);
    aff2_kernel<<<4096,256,0,stream>>>(dv, dh, llam, lmu, wv, wh, aff_out);
    // variance branch
    conv3x3<4,3,32,true ,float,bf16><<<cgrid,256,0,stream>>>(guide, ybic, vw1, vb1, bufA);
    conv3x3<32,32,32,true ,bf16,bf16><<<cgrid,256,0,stream>>>(bufA, bufA, vw2, vb2, bufB);
    conv3x3<32,32,1,false,bf16,float><<<cgrid,256,0,stream>>>(bufB, bufB, vw3, vb3, var_out);

    // CG: init + 2 fused dispatches per iteration
    hipMemsetAsync(scal, 0, 1024, stream);
    cg_init<<<1024,256,0,stream>>>(wv, wh, mask, source, ybic, llam,
                                   x_out, rr, pb0, scal);
    for (int k = 0; k < CG_ITERS; k++) {
        float* po = (k & 1) ? pb1 : pb0;
        float* pn = (k & 1) ? pb0 : pb1;
        cg_step1<<<1024,256,0,stream>>>(wv, wh, mask, llam, rr, po, pn, App, scal, k);
        cg_step2<<<1024,256,0,stream>>>(x_out, rr, pn, App, scal, k);
    }
}

// Round 8
// 4512.354 us; speedup vs baseline: 4.6812x; 1.3996x over previous
//
#include <hip/hip_runtime.h>
#include <hip/hip_bf16.h>

typedef __hip_bfloat16 bf16;
typedef __attribute__((ext_vector_type(8))) short short8;
typedef __attribute__((ext_vector_type(4))) float f32x4;

#define NB 16
#define PLANE (256*256)
#define CG_ITERS 100

static __device__ __forceinline__ short f2bf(float v){
    __hip_bfloat16 h = __float2bfloat16(v);
    short s; __builtin_memcpy(&s, &h, 2); return s;
}
static __device__ __forceinline__ float bf2f(short s){
    union { unsigned u; float f; } cv;
    cv.u = ((unsigned)(unsigned short)s) << 16; return cv.f;
}

// ---------------- first-layer conv 3x3 (small CIN, VALU), output channel-last bf16 ----------------
// block = 256 = 16x16 tile, grid (16,16,B). out[((n*256+y)*256+x)*32 + co]
template<int CIN, int SPLIT, bool RELU>
__global__ __launch_bounds__(256)
void conv3x3_first(const float* __restrict__ in, const float* __restrict__ in2,
                   const float* __restrict__ wgt, const float* __restrict__ bias,
                   bf16* __restrict__ out)
{
    __shared__ float s_in[CIN][18][18];
    __shared__ float s_w[CIN*9*32];
    const int n  = blockIdx.z;
    const int ty0 = blockIdx.y * 16, tx0 = blockIdx.x * 16;
    const int tid = threadIdx.x;

    for (int idx = tid; idx < CIN*9*32; idx += 256) {
        int co = idx & 31; int rest = idx >> 5;     // rest = ci*9 + k
        s_w[idx] = wgt[(co*CIN + rest/9)*9 + rest%9];
    }
    for (int idx = tid; idx < CIN*18*18; idx += 256) {
        int ci = idx / (18*18); int rr = idx % (18*18);
        int yy = rr / 18, xx = rr % 18;
        int y = ty0 + yy - 1, x = tx0 + xx - 1;
        float v = 0.f;
        if (y >= 0 && y < 256 && x >= 0 && x < 256) {
            if (ci < SPLIT) v = in [((size_t)(n*SPLIT + ci)*256 + y)*256 + x];
            else            v = in2[((size_t)(n*(CIN-SPLIT) + (ci-SPLIT))*256 + y)*256 + x];
        }
        s_in[ci][yy][xx] = v;
    }
    __syncthreads();

    const int ty = tid >> 4, tx = tid & 15;
    float acc[32];
    #pragma unroll
    for (int co = 0; co < 32; co++) acc[co] = bias[co];

    #pragma unroll
    for (int ci = 0; ci < CIN; ci++) {
        #pragma unroll
        for (int ky = 0; ky < 3; ky++)
        #pragma unroll
        for (int kx = 0; kx < 3; kx++) {
            float v = s_in[ci][ty+ky][tx+kx];
            const float* wp = &s_w[(ci*9 + ky*3 + kx)*32];
            #pragma unroll
            for (int co = 0; co < 32; co++) acc[co] = fmaf(v, wp[co], acc[co]);
        }
    }
    const int y = ty0 + ty, x = tx0 + tx;
    size_t base = (((size_t)n*256 + y)*256 + x)*32;
    #pragma unroll
    for (int c = 0; c < 32; c += 8) {
        short8 vv;
        #pragma unroll
        for (int j = 0; j < 8; j++) {
            float v = acc[c+j];
            if (RELU) v = fmaxf(v, 0.f);
            vv[j] = f2bf(v);
        }
        *(short8*)((short*)out + base + c) = vv;
    }
}

// ---------------- heavy conv 3x3 (32->32) via MFMA, channel-last bf16 in/out ----------------
// grid (xseg=16, ytile=16, n=16), block 256 = 4 waves. Wave w: rows ytile*16+w*4..+3,
// 16 px (xseg*16..+15), all 32 co (2 co-groups). Weights in VGPRs (B-frags), no LDS.
template<bool RELU>
__global__ __launch_bounds__(256)
void conv3x3_mfma(const bf16* __restrict__ in, const float* __restrict__ wgt,
                  const float* __restrict__ bias, bf16* __restrict__ out)
{
    const int lane = threadIdx.x & 63, wid = threadIdx.x >> 6;
    const int m = lane & 15, quad = lane >> 4, k0 = quad*8;
    const int n  = blockIdx.z;
    const int x0 = blockIdx.x * 16;
    const int y0 = blockIdx.y * 16 + wid * 4;

    // B-fragments: bw[g][tap] lane holds B[k=k0+j][n=g*16+m], j=0..7
    short8 bw[2][9];
    #pragma unroll
    for (int g = 0; g < 2; g++) {
        int co = g*16 + m;
        #pragma unroll
        for (int tap = 0; tap < 9; tap++) {
            short8 v;
            #pragma unroll
            for (int j = 0; j < 8; j++)
                v[j] = f2bf(wgt[(co*32 + (k0+j))*9 + tap]);
            bw[g][tap] = v;
        }
    }
    const float b0 = bias[m], b1 = bias[16 + m];

    const short* inp = (const short*)in + (size_t)n*PLANE*32;
    short* outp = (short*)out + (size_t)n*PLANE*32;

    #pragma unroll
    for (int r = 0; r < 4; r++) {
        const int y = y0 + r;
        f32x4 acc0 = { b0, b0, b0, b0 };
        f32x4 acc1 = { b1, b1, b1, b1 };
        #pragma unroll
        for (int ky = 0; ky < 3; ky++) {
            const int yy = y + ky - 1;
            const bool yok = (unsigned)yy < 256u;
            #pragma unroll
            for (int kx = 0; kx < 3; kx++) {
                const int xp = x0 + kx - 1 + m;
                short8 a = { 0,0,0,0,0,0,0,0 };
                if (yok && (unsigned)xp < 256u)
                    a = *(const short8*)(inp + ((size_t)yy*256 + xp)*32 + k0);
                acc0 = __builtin_amdgcn_mfma_f32_16x16x32_bf16(a, bw[0][ky*3+kx], acc0, 0, 0, 0);
                acc1 = __builtin_amdgcn_mfma_f32_16x16x32_bf16(a, bw[1][ky*3+kx], acc1, 0, 0, 0);
            }
        }
        // D layout: col(co)=lane&15, row(pixel)=quad*4+reg
        #pragma unroll
        for (int reg = 0; reg < 4; reg++) {
            int px = x0 + quad*4 + reg;
            size_t idx = ((size_t)y*256 + px)*32;
            float v0 = acc0[reg], v1 = acc1[reg];
            if (RELU) { v0 = fmaxf(v0, 0.f); v1 = fmaxf(v1, 0.f); }
            outp[idx + m]      = f2bf(v0);
            outp[idx + 16 + m] = f2bf(v1);
        }
    }
}

// ---------------- final conv 3x3 (32->1), channel-last input ----------------
__global__ __launch_bounds__(256)
void conv3x3_last(const bf16* __restrict__ in, const float* __restrict__ wgt,
                  const float* __restrict__ bias, float* __restrict__ out)
{
    __shared__ float s_w[288];
    int tid = threadIdx.x;
    for (int i = tid; i < 288; i += 256) s_w[i] = wgt[i];   // [ci*9+tap], strided load
    __syncthreads();
    int gid = blockIdx.x*256 + tid;
    int n = gid >> 16, h = (gid >> 8) & 255, w = gid & 255;
    const short* inp = (const short*)in + (size_t)n*PLANE*32;
    float sum = bias[0];
    #pragma unroll
    for (int ky = 0; ky < 3; ky++) {
        int yy = h + ky - 1;
        if ((unsigned)yy >= 256u) continue;
        #pragma unroll
        for (int kx = 0; kx < 3; kx++) {
            int xx = w + kx - 1;
            if ((unsigned)xx >= 256u) continue;
            const short8* pp = (const short8*)(inp + ((size_t)yy*256 + xx)*32);
            int tap = ky*3 + kx;
            #pragma unroll
            for (int c4 = 0; c4 < 4; c4++) {
                short8 v = pp[c4];
                #pragma unroll
                for (int j = 0; j < 8; j++)
                    sum = fmaf(bf2f(v[j]), s_w[(c4*8+j)*9 + tap], sum);
            }
        }
    }
    out[gid] = sum;
}

// ---------------- squared neighbor diffs over 32 channels, channel-last ----------------
template<bool ACCUM>
__global__ __launch_bounds__(256)
void dvdh_cl(const bf16* __restrict__ f, float* __restrict__ dv, float* __restrict__ dh)
{
    int bid = blockIdx.x;
    int n = bid >> 8, i = bid & 255, j = threadIdx.x;
    const short8* pc = (const short8*)((const short*)f + (((size_t)n*256 + i)*256 + j)*32);
    const short8* pr = (j < 255) ? pc + 4    : pc;   // right: +32 shorts  = +4 short8
    const short8* pd = (i < 255) ? pc + 1024 : pc;   // down: +256*32 shorts = +1024 short8
    float adv = 0.f, adh = 0.f;
    #pragma unroll
    for (int c4 = 0; c4 < 4; c4++) {
        short8 sc = pc[c4], sr = pr[c4], sd = pd[c4];
        #pragma unroll
        for (int e = 0; e < 8; e++) {
            float fc = bf2f(sc[e]);
            float d1 = bf2f(sr[e]) - fc;
            float d2 = bf2f(sd[e]) - fc;
            adh = fmaf(d1, d1, adh);
            adv = fmaf(d2, d2, adv);
        }
    }
    int o = (n*256 + i)*256 + j;
    if (ACCUM) { dv[o] += adv; dh[o] += adh; }
    else       { dv[o]  = adv; dh[o]  = adh; }
}

// ---------------- affinity: compact wv/wh (for CG) + 5-plane output ----------------
__global__ __launch_bounds__(256)
void aff2_kernel(const float* __restrict__ dv, const float* __restrict__ dh,
                 const float* __restrict__ llam, const float* __restrict__ lmu,
                 float* __restrict__ wv, float* __restrict__ wh,
                 float* __restrict__ aff)
{
    int bid = blockIdx.x;
    int n = bid >> 8, h = bid & 255, w = threadIdx.x;
    float mu = expf(lmu[0]), lam = expf(llam[0]);
    int rb = (n*256 + h)*256 + w;
    float wvv = (h < 255) ? expf(-mu * dv[rb]) : 0.f;
    float whv = (w < 255) ? expf(-mu * dh[rb]) : 0.f;
    wv[rb] = wvv; wh[rb] = whv;
    float w_up = (h > 0) ? expf(-mu * dv[rb - 256]) : 0.f;
    float w_lf = (w > 0) ? expf(-mu * dh[rb - 1])   : 0.f;
    float ctr  = w_up + wvv + w_lf + whv + lam;
    float* a = aff + ((size_t)n*5)*PLANE + h*256 + w;
    a[0]        = w_up;
    a[PLANE]    = wvv;
    a[2*PLANE]  = w_lf;
    a[3*PLANE]  = whv;
    a[4*PLANE]  = ctr;
}

// ---------------- shared reduction ----------------
static __device__ __forceinline__ void block_reduce_atomic(float v, float* dst, float* sh)
{
    #pragma unroll
    for (int o = 32; o > 0; o >>= 1) v += __shfl_down(v, o, 64);
    __syncthreads();
    if ((threadIdx.x & 63) == 0) sh[threadIdx.x >> 6] = v;
    __syncthreads();
    if (threadIdx.x == 0) atomicAdd(dst, sh[0]+sh[1]+sh[2]+sh[3]);
}

// ============ CG: 2 dispatches/iteration, tile-fused (proven R4 structure) ============
__global__ __launch_bounds__(256)
void cg_init(const float* __restrict__ wv, const float* __restrict__ wh,
             const float* __restrict__ mask, const float* __restrict__ src,
             const float* __restrict__ ybic, const float* __restrict__ llam,
             float* __restrict__ x, float* __restrict__ r, float* __restrict__ p0,
             float* __restrict__ scal)
{
    __shared__ float s_pn[34][35];
    __shared__ float s_part[128], s_bs[16], s_red[4];
    const int tid = threadIdx.x;
    const int b = blockIdx.x;
    const int n = b >> 6, t = b & 63;
    const int tyo = (t >> 3) * 32, txo = (t & 7) * 32;
    const int tx = tid & 31, tyb = tid >> 5;
    const int w = txo + tx;
    const float lam = expf(llam[0]);

    const float* ybn = ybic + (size_t)n*PLANE;
    float yv[4];
    #pragma unroll
    for (int i = 0; i < 4; i++) {
        int h = tyo + tyb + 8*i;
        yv[i] = ybn[h*256 + w];
        s_pn[1 + tyb + 8*i][1 + tx] = yv[i];
    }
    if (tid < 128) {
        int which = tid >> 5, lane = tid & 31;
        int y, xx;
        if      (which == 0) { y = tyo - 1;    xx = txo + lane; }
        else if (which == 1) { y = tyo + 32;   xx = txo + lane; }
        else if (which == 2) { y = tyo + lane; xx = txo - 1;    }
        else                 { y = tyo + lane; xx = txo + 32;   }
        float v = 0.f;
        if (y >= 0 && y < 256 && xx >= 0 && xx < 256) v = ybn[y*256 + xx];
        s_pn[y - tyo + 1][xx - txo + 1] = v;
    }
    __syncthreads();
    if (tid < 128) {
        int blk = tid >> 3, rib = tid & 7;
        const float* rw = &s_pn[1 + (blk>>2)*8 + rib][1 + (blk&3)*8];
        s_part[tid] = rw[0]+rw[1]+rw[2]+rw[3]+rw[4]+rw[5]+rw[6]+rw[7];
    }
    __syncthreads();
    if (tid < 16) {
        const float* q = s_part + tid*8;
        s_bs[tid] = q[0]+q[1]+q[2]+q[3]+q[4]+q[5]+q[6]+q[7];
    }
    __syncthreads();

    const float* wvn = wv + (size_t)n*PLANE;
    const float* whn = wh + (size_t)n*PLANE;
    float* rn = r  + (size_t)n*PLANE;
    float* pn = p0 + (size_t)n*PLANE;
    float* xn = x  + (size_t)n*PLANE;
    float g0 = 0.f;
    #pragma unroll
    for (int i = 0; i < 4; i++) {
        int h = tyo + tyb + 8*i;
        int idx = h*256 + w;
        int yy = 1 + tyb + 8*i, xx = 1 + tx;
        float wvu = (h > 0) ? wvn[idx-256] : 0.f;
        float wvd = wvn[idx];
        float whl = (w > 0) ? whn[idx-1] : 0.f;
        float whr = whn[idx];
        float s = wvu*s_pn[yy-1][xx] + wvd*s_pn[yy+1][xx]
                + whl*s_pn[yy][xx-1] + whr*s_pn[yy][xx+1];
        float deg = wvu+wvd+whl+whr;
        int bi = n*1024 + (h>>3)*32 + (w>>3);
        float mv = mask[bi];
        float ax = deg*s_pn[yy][xx] - s + lam*mv*(1.f/4096.f)*s_bs[i*4 + (tx>>3)];
        float brhs = lam*mv*src[bi]*(1.f/64.f);
        float r0 = brhs - ax;
        rn[idx] = r0; pn[idx] = r0; xn[idx] = yv[i];
        g0 += r0*r0;
    }
    block_reduce_atomic(g0, &scal[0], s_red);
}

__global__ __launch_bounds__(256)
void cg_step1(const float* __restrict__ wv, const float* __restrict__ wh,
              const float* __restrict__ mask, const float* __restrict__ llam,
              const float* __restrict__ r, const float* __restrict__ pold,
              float* __restrict__ pnew, float* __restrict__ Ap,
              float* __restrict__ scal, int k)
{
    __shared__ float s_pn[34][35];
    __shared__ float s_part[128], s_bs[16], s_red[4];
    const int tid = threadIdx.x;
    const int b = blockIdx.x;
    const int n = b >> 6, t = b & 63;
    const int tyo = (t >> 3) * 32, txo = (t & 7) * 32;
    const int tx = tid & 31, tyb = tid >> 5;
    const int w = txo + tx;
    const float lam = expf(llam[0]);
    const float beta = (k == 0) ? 0.f : scal[k] / scal[k-1];

    const float* rn = r    + (size_t)n*PLANE;
    const float* po = pold + (size_t)n*PLANE;

    float pv[4];
    #pragma unroll
    for (int i = 0; i < 4; i++) {
        int h = tyo + tyb + 8*i;
        int idx = h*256 + w;
        pv[i] = fmaf(beta, po[idx], rn[idx]);
        s_pn[1 + tyb + 8*i][1 + tx] = pv[i];
    }
    if (tid < 128) {
        int which = tid >> 5, lane = tid & 31;
        int y, xx;
        if      (which == 0) { y = tyo - 1;    xx = txo + lane; }
        else if (which == 1) { y = tyo + 32;   xx = txo + lane; }
        else if (which == 2) { y = tyo + lane; xx = txo - 1;    }
        else                 { y = tyo + lane; xx = txo + 32;   }
        float v = 0.f;
        if (y >= 0 && y < 256 && xx >= 0 && xx < 256) {
            int idx = y*256 + xx;
            v = fmaf(beta, po[idx], rn[idx]);
        }
        s_pn[y - tyo + 1][xx - txo + 1] = v;
    }
    __syncthreads();
    if (tid < 128) {
        int blk = tid >> 3, rib = tid & 7;
        const float* rw = &s_pn[1 + (blk>>2)*8 + rib][1 + (blk&3)*8];
        s_part[tid] = rw[0]+rw[1]+rw[2]+rw[3]+rw[4]+rw[5]+rw[6]+rw[7];
    }
    __syncthreads();
    if (tid < 16) {
        const float* q = s_part + tid*8;
        s_bs[tid] = q[0]+q[1]+q[2]+q[3]+q[4]+q[5]+q[6]+q[7];
    }
    __syncthreads();

    const float* wvn = wv + (size_t)n*PLANE;
    const float* whn = wh + (size_t)n*PLANE;
    float* pw  = pnew + (size_t)n*PLANE;
    float* Apn = Ap   + (size_t)n*PLANE;
    float lsum = 0.f;
    #pragma unroll
    for (int i = 0; i < 4; i++) {
        int h = tyo + tyb + 8*i;
        int idx = h*256 + w;
        int yy = 1 + tyb + 8*i, xx = 1 + tx;
        float wvu = (h > 0) ? wvn[idx-256] : 0.f;
        float wvd = wvn[idx];
        float whl = (w > 0) ? whn[idx-1] : 0.f;
        float whr = whn[idx];
        float s = wvu*s_pn[yy-1][xx] + wvd*s_pn[yy+1][xx]
                + whl*s_pn[yy][xx-1] + whr*s_pn[yy][xx+1];
        float deg = wvu+wvd+whl+whr;
        int bi = n*1024 + (h>>3)*32 + (w>>3);
        float c1 = lam*mask[bi]*(1.f/4096.f);
        float ap = deg*s_pn[yy][xx] - s + c1*s_bs[i*4 + (tx>>3)];
        Apn[idx] = ap;
        pw[idx]  = pv[i];
        lsum += pv[i]*ap;
    }
    block_reduce_atomic(lsum, &scal[128+k], s_red);
}

__global__ __launch_bounds__(256)
void cg_step2(float* __restrict__ x, float* __restrict__ r,
              const float* __restrict__ p, const float* __restrict__ Ap,
              float* __restrict__ scal, int k)
{
    __shared__ float s_red[4];
    int g = blockIdx.x*256 + threadIdx.x;       // float4 index
    float alpha = scal[k] / scal[128+k];
    float4 pv = ((const float4*)p)[g];
    float4 av = ((const float4*)Ap)[g];
    float4 xv = ((float4*)x)[g];
    float4 rv = ((float4*)r)[g];
    xv.x = fmaf(alpha, pv.x, xv.x); rv.x = fmaf(-alpha, av.x, rv.x);
    xv.y = fmaf(alpha, pv.y, xv.y); rv.y = fmaf(-alpha, av.y, rv.y);
    xv.z = fmaf(alpha, pv.z, xv.z); rv.z = fmaf(-alpha, av.z, rv.z);
    xv.w = fmaf(alpha, pv.w, xv.w); rv.w = fmaf(-alpha, av.w, rv.w);
    ((float4*)x)[g] = xv;
    ((float4*)r)[g] = rv;
    float gn = rv.x*rv.x + rv.y*rv.y + rv.z*rv.z + rv.w*rv.w;
    block_reduce_atomic(gn, &scal[k+1], s_red);
}

// ---------------- host ----------------
extern "C" void kernel_launch(void* const* d_in, const int* in_sizes, int n_in,
                              void* d_out, int out_size, void* d_ws, size_t ws_size,
                              hipStream_t stream)
{
    (void)in_sizes; (void)n_in; (void)out_size; (void)ws_size;
    const float* guide = (const float*)d_in[0];
    const float* source= (const float*)d_in[1];
    const float* mask  = (const float*)d_in[2];
    const float* ybic  = (const float*)d_in[3];
    const float* gw1 = (const float*)d_in[4];  const float* gb1 = (const float*)d_in[5];
    const float* gw2 = (const float*)d_in[6];  const float* gb2 = (const float*)d_in[7];
    const float* sw1 = (const float*)d_in[8];  const float* sb1 = (const float*)d_in[9];
    const float* sw2 = (const float*)d_in[10]; const float* sb2 = (const float*)d_in[11];
    const float* vw1 = (const float*)d_in[12]; const float* vb1 = (const float*)d_in[13];
    const float* vw2 = (const float*)d_in[14]; const float* vb2 = (const float*)d_in[15];
    const float* vw3 = (const float*)d_in[16]; const float* vb3 = (const float*)d_in[17];
    const float* llam = (const float*)d_in[18];
    const float* lmu  = (const float*)d_in[19];

    float* out     = (float*)d_out;
    float* x_out   = out;                 // y_pred (16,1,256,256)
    float* var_out = out + 1048576;       // var
    float* aff_out = out + 2097152;       // aff (16,5,256,256)

    char* ws = (char*)d_ws;
    size_t o = 0;
    bf16* tmp1 = (bf16*)(ws + o); o += (size_t)NB*32*PLANE*2;   // CL32
    bf16* tmp2 = (bf16*)(ws + o); o += (size_t)NB*32*PLANE*2;   // CL32
    float* dv  = (float*)(ws + o); o += (size_t)NB*PLANE*4;
    float* dh  = (float*)(ws + o); o += (size_t)NB*PLANE*4;
    float* wv  = (float*)(ws + o); o += (size_t)NB*PLANE*4;
    float* wh  = (float*)(ws + o); o += (size_t)NB*PLANE*4;
    float* pb0 = (float*)(ws + o); o += (size_t)NB*PLANE*4;
    float* pb1 = (float*)(ws + o); o += (size_t)NB*PLANE*4;
    float* rr  = (float*)(ws + o); o += (size_t)NB*PLANE*4;
    float* App = (float*)(ws + o); o += (size_t)NB*PLANE*4;
    float* scal= (float*)(ws + o); o += 1024;

    dim3 cgrid(16, 16, NB);

    // feature branch g = conv(relu(conv(guide)))
    conv3x3_first<3,3,true><<<cgrid,256,0,stream>>>(guide, guide, gw1, gb1, tmp1);
    conv3x3_mfma<false><<<cgrid,256,0,stream>>>(tmp1, gw2, gb2, tmp2);
    dvdh_cl<false><<<4096,256,0,stream>>>(tmp2, dv, dh);
    // feature branch s = conv(relu(conv(y_bicubic)))
    conv3x3_first<1,1,true><<<cgrid,256,0,stream>>>(ybic, ybic, sw1, sb1, tmp1);
    conv3x3_mfma<false><<<cgrid,256,0,stream>>>(tmp1, sw2, sb2, tmp2);
    dvdh_cl<true><<<4096,256,0,stream>>>(tmp2, dv, dh);
    aff2_kernel<<<4096,256,0,stream>>>(dv, dh, llam, lmu, wv, wh, aff_out);
    // variance branch
    conv3x3_first<4,3,true><<<cgrid,256,0,stream>>>(guide, ybic, vw1, vb1, tmp1);
    conv3x3_mfma<true><<<cgrid,256,0,stream>>>(tmp1, vw2, vb2, tmp2);
    conv3x3_last<<<4096,256,0,stream>>>(tmp2, vw3, vb3, var_out);

    // CG: init + 2 fused dispatches per iteration
    hipMemsetAsync(scal, 0, 1024, stream);
    cg_init<<<1024,256,0,stream>>>(wv, wh, mask, source, ybic, llam,
                                   x_out, rr, pb0, scal);
    for (int k = 0; k < CG_ITERS; k++) {
        float* po = (k & 1) ? pb1 : pb0;
        float* pn = (k & 1) ? pb0 : pb1;
        cg_step1<<<1024,256,0,stream>>>(wv, wh, mask, llam, rr, po, pn, App, scal, k);
        cg_step2<<<1024,256,0,stream>>>(x_out, rr, pn, App, scal, k);
    }
}

// Round 12
// 2961.501 us; speedup vs baseline: 7.1326x; 1.5237x over previous
//
#include <hip/hip_runtime.h>
#include <hip/hip_bf16.h>

typedef __hip_bfloat16 bf16;
typedef __attribute__((ext_vector_type(8))) short short8;
typedef __attribute__((ext_vector_type(4))) float f32x4;

#define NB 16
#define PLANE (256*256)

static __device__ __forceinline__ short f2bf(float v){
    __hip_bfloat16 h = __float2bfloat16(v);
    short s; __builtin_memcpy(&s, &h, 2); return s;
}
static __device__ __forceinline__ float bf2f(short s){
    union { unsigned u; float f; } cv;
    cv.u = ((unsigned)(unsigned short)s) << 16; return cv.f;
}

// ---------------- first-layer conv 3x3 (small CIN, VALU), output channel-last bf16 ----------------
template<int CIN, int SPLIT, bool RELU>
__global__ __launch_bounds__(256)
void conv3x3_first(const float* __restrict__ in, const float* __restrict__ in2,
                   const float* __restrict__ wgt, const float* __restrict__ bias,
                   bf16* __restrict__ out)
{
    __shared__ float s_in[CIN][18][18];
    __shared__ float s_w[CIN*9*32];
    const int n  = blockIdx.z;
    const int ty0 = blockIdx.y * 16, tx0 = blockIdx.x * 16;
    const int tid = threadIdx.x;

    for (int idx = tid; idx < CIN*9*32; idx += 256) {
        int co = idx & 31; int rest = idx >> 5;     // rest = ci*9 + k
        s_w[idx] = wgt[(co*CIN + rest/9)*9 + rest%9];
    }
    for (int idx = tid; idx < CIN*18*18; idx += 256) {
        int ci = idx / (18*18); int rr = idx % (18*18);
        int yy = rr / 18, xx = rr % 18;
        int y = ty0 + yy - 1, x = tx0 + xx - 1;
        float v = 0.f;
        if (y >= 0 && y < 256 && x >= 0 && x < 256) {
            if (ci < SPLIT) v = in [((size_t)(n*SPLIT + ci)*256 + y)*256 + x];
            else            v = in2[((size_t)(n*(CIN-SPLIT) + (ci-SPLIT))*256 + y)*256 + x];
        }
        s_in[ci][yy][xx] = v;
    }
    __syncthreads();

    const int ty = tid >> 4, tx = tid & 15;
    float acc[32];
    #pragma unroll
    for (int co = 0; co < 32; co++) acc[co] = bias[co];

    #pragma unroll
    for (int ci = 0; ci < CIN; ci++) {
        #pragma unroll
        for (int ky = 0; ky < 3; ky++)
        #pragma unroll
        for (int kx = 0; kx < 3; kx++) {
            float v = s_in[ci][ty+ky][tx+kx];
            const float* wp = &s_w[(ci*9 + ky*3 + kx)*32];
            #pragma unroll
            for (int co = 0; co < 32; co++) acc[co] = fmaf(v, wp[co], acc[co]);
        }
    }
    const int y = ty0 + ty, x = tx0 + tx;
    size_t base = (((size_t)n*256 + y)*256 + x)*32;
    #pragma unroll
    for (int c = 0; c < 32; c += 8) {
        short8 vv;
        #pragma unroll
        for (int j = 0; j < 8; j++) {
            float v = acc[c+j];
            if (RELU) v = fmaxf(v, 0.f);
            vv[j] = f2bf(v);
        }
        *(short8*)((short*)out + base + c) = vv;
    }
}

// ---------------- weight repack for MFMA convs: [co][ci][tap] f32 -> [tap][co][ci] bf16 ----------------
__global__ __launch_bounds__(256)
void wrepack3(const float* __restrict__ a, const float* __restrict__ b,
              const float* __restrict__ c,
              bf16* __restrict__ oa, bf16* __restrict__ ob, bf16* __restrict__ oc)
{
    int j = blockIdx.x*256 + threadIdx.x;        // 0..27647
    if (j >= 3*9216) return;
    int set = j / 9216, r = j % 9216;
    int tap = r >> 10, rem = r & 1023, co = rem >> 5, ci = rem & 31;
    const float* src = (set == 0) ? a : (set == 1) ? b : c;
    bf16* dst = (set == 0) ? oa : (set == 1) ? ob : oc;
    dst[r] = __float2bfloat16(src[(co*32 + ci)*9 + tap]);
}

// ---------------- heavy conv 3x3 (32->32) via MFMA, channel-last bf16 in/out ----------------
// weights pre-packed [tap][co][ci] bf16 -> 18 coalesced short8 loads per wave
template<bool RELU>
__global__ __launch_bounds__(256)
void conv3x3_mfma(const bf16* __restrict__ in, const bf16* __restrict__ wpk,
                  const float* __restrict__ bias, bf16* __restrict__ out)
{
    const int lane = threadIdx.x & 63, wid = threadIdx.x >> 6;
    const int m = lane & 15, quad = lane >> 4, k0 = quad*8;
    const int n  = blockIdx.z;
    const int x0 = blockIdx.x * 16;
    const int y0 = blockIdx.y * 16 + wid * 4;

    const short* wp = (const short*)wpk;
    short8 bw[2][9];
    #pragma unroll
    for (int g = 0; g < 2; g++)
        #pragma unroll
        for (int tap = 0; tap < 9; tap++)
            bw[g][tap] = *(const short8*)(wp + ((tap*32 + g*16 + m)*32 + k0));
    const float b0 = bias[m], b1 = bias[16 + m];

    const short* inp = (const short*)in + (size_t)n*PLANE*32;
    short* outp = (short*)out + (size_t)n*PLANE*32;

    #pragma unroll
    for (int r = 0; r < 4; r++) {
        const int y = y0 + r;
        f32x4 acc0 = { b0, b0, b0, b0 };
        f32x4 acc1 = { b1, b1, b1, b1 };
        #pragma unroll
        for (int ky = 0; ky < 3; ky++) {
            const int yy = y + ky - 1;
            const bool yok = (unsigned)yy < 256u;
            #pragma unroll
            for (int kx = 0; kx < 3; kx++) {
                const int xp = x0 + kx - 1 + m;
                short8 a = { 0,0,0,0,0,0,0,0 };
                if (yok && (unsigned)xp < 256u)
                    a = *(const short8*)(inp + ((size_t)yy*256 + xp)*32 + k0);
                acc0 = __builtin_amdgcn_mfma_f32_16x16x32_bf16(a, bw[0][ky*3+kx], acc0, 0, 0, 0);
                acc1 = __builtin_amdgcn_mfma_f32_16x16x32_bf16(a, bw[1][ky*3+kx], acc1, 0, 0, 0);
            }
        }
        #pragma unroll
        for (int reg = 0; reg < 4; reg++) {
            int px = x0 + quad*4 + reg;
            size_t idx = ((size_t)y*256 + px)*32;
            float v0 = acc0[reg], v1 = acc1[reg];
            if (RELU) { v0 = fmaxf(v0, 0.f); v1 = fmaxf(v1, 0.f); }
            outp[idx + m]      = f2bf(v0);
            outp[idx + 16 + m] = f2bf(v1);
        }
    }
}

// ---------------- final conv 3x3 (32->1), channel-last input ----------------
__global__ __launch_bounds__(256)
void conv3x3_last(const bf16* __restrict__ in, const float* __restrict__ wgt,
                  const float* __restrict__ bias, float* __restrict__ out)
{
    __shared__ float s_w[288];
    int tid = threadIdx.x;
    for (int i = tid; i < 288; i += 256) s_w[i] = wgt[i];
    __syncthreads();
    int gid = blockIdx.x*256 + tid;
    int n = gid >> 16, h = (gid >> 8) & 255, w = gid & 255;
    const short* inp = (const short*)in + (size_t)n*PLANE*32;
    float sum = bias[0];
    #pragma unroll
    for (int ky = 0; ky < 3; ky++) {
        int yy = h + ky - 1;
        if ((unsigned)yy >= 256u) continue;
        #pragma unroll
        for (int kx = 0; kx < 3; kx++) {
            int xx = w + kx - 1;
            if ((unsigned)xx >= 256u) continue;
            const short8* pp = (const short8*)(inp + ((size_t)yy*256 + xx)*32);
            int tap = ky*3 + kx;
            #pragma unroll
            for (int c4 = 0; c4 < 4; c4++) {
                short8 v = pp[c4];
                #pragma unroll
                for (int j = 0; j < 8; j++)
                    sum = fmaf(bf2f(v[j]), s_w[(c4*8+j)*9 + tap], sum);
            }
        }
    }
    out[gid] = sum;
}

// ---------------- squared neighbor diffs over 32 channels, channel-last ----------------
template<bool ACCUM>
__global__ __launch_bounds__(256)
void dvdh_cl(const bf16* __restrict__ f, float* __restrict__ dv, float* __restrict__ dh)
{
    int bid = blockIdx.x;
    int n = bid >> 8, i = bid & 255, j = threadIdx.x;
    const short8* pc = (const short8*)((const short*)f + (((size_t)n*256 + i)*256 + j)*32);
    const short8* pr = (j < 255) ? pc + 4    : pc;
    const short8* pd = (i < 255) ? pc + 1024 : pc;
    float adv = 0.f, adh = 0.f;
    #pragma unroll
    for (int c4 = 0; c4 < 4; c4++) {
        short8 sc = pc[c4], sr = pr[c4], sd = pd[c4];
        #pragma unroll
        for (int e = 0; e < 8; e++) {
            float fc = bf2f(sc[e]);
            float d1 = bf2f(sr[e]) - fc;
            float d2 = bf2f(sd[e]) - fc;
            adh = fmaf(d1, d1, adh);
            adv = fmaf(d2, d2, adv);
        }
    }
    int o = (n*256 + i)*256 + j;
    if (ACCUM) { dv[o] += adv; dh[o] += adh; }
    else       { dv[o]  = adv; dh[o]  = adh; }
}

// ---------------- affinity: packed bf16 (wv,wh) for CG + 5-plane fp32 output ----------------
__global__ __launch_bounds__(256)
void aff2_kernel(const float* __restrict__ dv, const float* __restrict__ dh,
                 const float* __restrict__ llam, const float* __restrict__ lmu,
                 unsigned* __restrict__ wvh, float* __restrict__ aff)
{
    int bid = blockIdx.x;
    int n = bid >> 8, h = bid & 255, w = threadIdx.x;
    float mu = expf(lmu[0]), lam = expf(llam[0]);
    int rb = (n*256 + h)*256 + w;
    float wvv = (h < 255) ? expf(-mu * dv[rb]) : 0.f;
    float whv = (w < 255) ? expf(-mu * dh[rb]) : 0.f;
    unsigned pv = (unsigned)(unsigned short)f2bf(wvv);
    unsigned ph = (unsigned)(unsigned short)f2bf(whv);
    wvh[rb] = pv | (ph << 16);
    float w_up = (h > 0) ? expf(-mu * dv[rb - 256]) : 0.f;
    float w_lf = (w > 0) ? expf(-mu * dh[rb - 1])   : 0.f;
    float ctr  = w_up + wvv + w_lf + whv + lam;
    float* a = aff + ((size_t)n*5)*PLANE + h*256 + w;
    a[0]        = w_up;
    a[PLANE]    = wvv;
    a[2*PLANE]  = w_lf;
    a[3*PLANE]  = whv;
    a[4*PLANE]  = ctr;
}

// ---------------- shared reduction ----------------
static __device__ __forceinline__ void block_reduce_atomic(float v, float* dst, float* sh)
{
    #pragma unroll
    for (int o = 32; o > 0; o >>= 1) v += __shfl_down(v, o, 64);
    __syncthreads();
    if ((threadIdx.x & 63) == 0) sh[threadIdx.x >> 6] = v;
    __syncthreads();
    if (threadIdx.x == 0) atomicAdd(dst, sh[0]+sh[1]+sh[2]+sh[3]);
}

// stencil weight unpack: wvd=lo(wvh[idx]), whr=hi(wvh[idx]); wvu=lo(idx-256); whl=hi(idx-1)
static __device__ __forceinline__ void ld_w(const unsigned* __restrict__ wvh,
    int idx, int h, int w, float& wvu, float& wvd, float& whl, float& whr)
{
    unsigned c = wvh[idx];
    wvd = bf2f((short)(c & 0xffff));
    whr = bf2f((short)(c >> 16));
    wvu = (h > 0) ? bf2f((short)(wvh[idx-256] & 0xffff)) : 0.f;
    whl = (w > 0) ? bf2f((short)(wvh[idx-1] >> 16))      : 0.f;
}

// ============ CG ============
// scal: gamma_real[k]=scal[k] (0..100), pAp[k]=scal[128+k], ApAp[k]=scal[256+k]

__global__ __launch_bounds__(256)
void cg_init(const unsigned* __restrict__ wvh,
             const float* __restrict__ mask, const float* __restrict__ src,
             const float* __restrict__ ybic, const float* __restrict__ llam,
             float* __restrict__ x, float* __restrict__ r, float* __restrict__ p0,
             float* __restrict__ scal)
{
    __shared__ float s_pn[34][35];
    __shared__ float s_part[128], s_bs[16], s_red[4];
    const int tid = threadIdx.x;
    const int b = blockIdx.x;
    const int n = b >> 6, t = b & 63;
    const int tyo = (t >> 3) * 32, txo = (t & 7) * 32;
    const int tx = tid & 31, tyb = tid >> 5;
    const int w = txo + tx;
    const float lam = expf(llam[0]);

    const float* ybn = ybic + (size_t)n*PLANE;
    float yv[4];
    #pragma unroll
    for (int i = 0; i < 4; i++) {
        int h = tyo + tyb + 8*i;
        yv[i] = ybn[h*256 + w];
        s_pn[1 + tyb + 8*i][1 + tx] = yv[i];
    }
    if (tid < 128) {
        int which = tid >> 5, lane = tid & 31;
        int y, xx;
        if      (which == 0) { y = tyo - 1;    xx = txo + lane; }
        else if (which == 1) { y = tyo + 32;   xx = txo + lane; }
        else if (which == 2) { y = tyo + lane; xx = txo - 1;    }
        else                 { y = tyo + lane; xx = txo + 32;   }
        float v = 0.f;
        if (y >= 0 && y < 256 && xx >= 0 && xx < 256) v = ybn[y*256 + xx];
        s_pn[y - tyo + 1][xx - txo + 1] = v;
    }
    __syncthreads();
    if (tid < 128) {
        int blk = tid >> 3, rib = tid & 7;
        const float* rw = &s_pn[1 + (blk>>2)*8 + rib][1 + (blk&3)*8];
        s_part[tid] = rw[0]+rw[1]+rw[2]+rw[3]+rw[4]+rw[5]+rw[6]+rw[7];
    }
    __syncthreads();
    if (tid < 16) {
        const float* q = s_part + tid*8;
        s_bs[tid] = q[0]+q[1]+q[2]+q[3]+q[4]+q[5]+q[6]+q[7];
    }
    __syncthreads();

    const unsigned* wn = wvh + (size_t)n*PLANE;
    float* rn = r  + (size_t)n*PLANE;
    float* pn = p0 + (size_t)n*PLANE;
    float* xn = x  + (size_t)n*PLANE;
    float g0 = 0.f;
    #pragma unroll
    for (int i = 0; i < 4; i++) {
        int h = tyo + tyb + 8*i;
        int idx = h*256 + w;
        int yy = 1 + tyb + 8*i, xx = 1 + tx;
        float wvu, wvd, whl, whr;
        ld_w(wn, idx, h, w, wvu, wvd, whl, whr);
        float s = wvu*s_pn[yy-1][xx] + wvd*s_pn[yy+1][xx]
                + whl*s_pn[yy][xx-1] + whr*s_pn[yy][xx+1];
        float deg = wvu+wvd+whl+whr;
        int bi = n*1024 + (h>>3)*32 + (w>>3);
        float mv = mask[bi];
        float ax = deg*s_pn[yy][xx] - s + lam*mv*(1.f/4096.f)*s_bs[i*4 + (tx>>3)];
        float brhs = lam*mv*src[bi]*(1.f/64.f);
        float r0 = brhs - ax;
        rn[idx] = r0; pn[idx] = r0; xn[idx] = yv[i];
        g0 += r0*r0;
    }
    block_reduce_atomic(g0, &scal[0], s_red);
}

// fused iteration k (non-FIRST): alpha = g[k-1]/pAp[k-1] (real);
// beta = (alpha^2*ApAp[k-1] - g[k-1]) / g[k-1] (one-step recurrence);
// r_new = r - alpha*Ap; x += alpha*p; p_new = r_new + beta*p;
// Ap_new = A p_new; reduce pAp[k], ApAp[k], g_real[k].
// FIRST (k=0): no updates; Ap_0 = A p_0; reduce pAp[0], ApAp[0].
template<bool FIRST>
__global__ __launch_bounds__(256)
void cg_fused(const unsigned* __restrict__ wvh, const float* __restrict__ mask,
              const float* __restrict__ llam,
              const float* __restrict__ r_old, const float* __restrict__ p_old,
              const float* __restrict__ Ap_old, float* __restrict__ x,
              float* __restrict__ r_new, float* __restrict__ p_new,
              float* __restrict__ Ap_new, float* __restrict__ scal, int k)
{
    __shared__ float s_pn[34][35];
    __shared__ float s_part[128], s_bs[16], s_red[4];
    const int tid = threadIdx.x;
    const int b = blockIdx.x;
    const int n = b >> 6, t = b & 63;
    const int tyo = (t >> 3) * 32, txo = (t & 7) * 32;
    const int tx = tid & 31, tyb = tid >> 5;
    const int w = txo + tx;
    const float lam = expf(llam[0]);

    float alpha = 0.f, beta = 0.f;
    if (!FIRST) {
        float gprev = scal[k-1], pap = scal[128+k-1], apap = scal[256+k-1];
        alpha = gprev / pap;
        float grec = alpha*alpha*apap - gprev;
        beta = grec / gprev;
    }

    const float* ro = r_old  + (size_t)n*PLANE;
    const float* po = p_old  + (size_t)n*PLANE;
    const float* ao = Ap_old + (size_t)n*PLANE;
    float* xn  = x      + (size_t)n*PLANE;
    float* rw  = r_new  + (size_t)n*PLANE;
    float* pw  = p_new  + (size_t)n*PLANE;
    float* apw = Ap_new + (size_t)n*PLANE;

    float pv[4], gsum = 0.f;
    #pragma unroll
    for (int i = 0; i < 4; i++) {
        int h = tyo + tyb + 8*i;
        int idx = h*256 + w;
        float pO = po[idx];
        float pN;
        if (FIRST) {
            pN = pO;
        } else {
            float rN = fmaf(-alpha, ao[idx], ro[idx]);
            xn[idx] = fmaf(alpha, pO, xn[idx]);
            pN = fmaf(beta, pO, rN);
            rw[idx] = rN;
            pw[idx] = pN;
            gsum += rN*rN;
        }
        pv[i] = pN;
        s_pn[1 + tyb + 8*i][1 + tx] = pN;
    }
    if (tid < 128) {
        int which = tid >> 5, lane = tid & 31;
        int y, xx;
        if      (which == 0) { y = tyo - 1;    xx = txo + lane; }
        else if (which == 1) { y = tyo + 32;   xx = txo + lane; }
        else if (which == 2) { y = tyo + lane; xx = txo - 1;    }
        else                 { y = tyo + lane; xx = txo + 32;   }
        float v = 0.f;
        if (y >= 0 && y < 256 && xx >= 0 && xx < 256) {
            int idx = y*256 + xx;
            if (FIRST) v = po[idx];
            else       v = fmaf(beta, po[idx], fmaf(-alpha, ao[idx], ro[idx]));
        }
        s_pn[y - tyo + 1][xx - txo + 1] = v;
    }
    __syncthreads();
    if (tid < 128) {
        int blk = tid >> 3, rib = tid & 7;
        const float* rr = &s_pn[1 + (blk>>2)*8 + rib][1 + (blk&3)*8];
        s_part[tid] = rr[0]+rr[1]+rr[2]+rr[3]+rr[4]+rr[5]+rr[6]+rr[7];
    }
    __syncthreads();
    if (tid < 16) {
        const float* q = s_part + tid*8;
        s_bs[tid] = q[0]+q[1]+q[2]+q[3]+q[4]+q[5]+q[6]+q[7];
    }
    __syncthreads();

    const unsigned* wn = wvh + (size_t)n*PLANE;
    float papsum = 0.f, apapsum = 0.f;
    #pragma unroll
    for (int i = 0; i < 4; i++) {
        int h = tyo + tyb + 8*i;
        int idx = h*256 + w;
        int yy = 1 + tyb + 8*i, xx = 1 + tx;
        float wvu, wvd, whl, whr;
        ld_w(wn, idx, h, w, wvu, wvd, whl, whr);
        float s = wvu*s_pn[yy-1][xx] + wvd*s_pn[yy+1][xx]
                + whl*s_pn[yy][xx-1] + whr*s_pn[yy][xx+1];
        float deg = wvu+wvd+whl+whr;
        int bi = n*1024 + (h>>3)*32 + (w>>3);
        float c1 = lam*mask[bi]*(1.f/4096.f);
        float ap = deg*s_pn[yy][xx] - s + c1*s_bs[i*4 + (tx>>3)];
        apw[idx] = ap;
        papsum  += pv[i]*ap;
        apapsum += ap*ap;
    }
    block_reduce_atomic(papsum,  &scal[128+k], s_red);
    block_reduce_atomic(apapsum, &scal[256+k], s_red);
    if (!FIRST) block_reduce_atomic(gsum, &scal[k], s_red);
}

// tail: x += alpha_99 * p_99
__global__ __launch_bounds__(256)
void cg_lastx(float* __restrict__ x, const float* __restrict__ p,
              const float* __restrict__ scal)
{
    int g = blockIdx.x*256 + threadIdx.x;
    float alpha = scal[99] / scal[128+99];
    float4 pv = ((const float4*)p)[g];
    float4 xv = ((float4*)x)[g];
    xv.x = fmaf(alpha, pv.x, xv.x);
    xv.y = fmaf(alpha, pv.y, xv.y);
    xv.z = fmaf(alpha, pv.z, xv.z);
    xv.w = fmaf(alpha, pv.w, xv.w);
    ((float4*)x)[g] = xv;
}

// ---------------- host ----------------
extern "C" void kernel_launch(void* const* d_in, const int* in_sizes, int n_in,
                              void* d_out, int out_size, void* d_ws, size_t ws_size,
                              hipStream_t stream)
{
    (void)in_sizes; (void)n_in; (void)out_size; (void)ws_size;
    const float* guide = (const float*)d_in[0];
    const float* source= (const float*)d_in[1];
    const float* mask  = (const float*)d_in[2];
    const float* ybic  = (const float*)d_in[3];
    const float* gw1 = (const float*)d_in[4];  const float* gb1 = (const float*)d_in[5];
    const float* gw2 = (const float*)d_in[6];  const float* gb2 = (const float*)d_in[7];
    const float* sw1 = (const float*)d_in[8];  const float* sb1 = (const float*)d_in[9];
    const float* sw2 = (const float*)d_in[10]; const float* sb2 = (const float*)d_in[11];
    const float* vw1 = (const float*)d_in[12]; const float* vb1 = (const float*)d_in[13];
    const float* vw2 = (const float*)d_in[14]; const float* vb2 = (const float*)d_in[15];
    const float* vw3 = (const float*)d_in[16]; const float* vb3 = (const float*)d_in[17];
    const float* llam = (const float*)d_in[18];
    const float* lmu  = (const float*)d_in[19];

    float* out     = (float*)d_out;
    float* x_out   = out;                 // y_pred (16,1,256,256)
    float* var_out = out + 1048576;       // var
    float* aff_out = out + 2097152;       // aff (16,5,256,256)

    // ---- workspace layout (total ~140.1 MiB, small persistent objects FIRST;
    //      CG vectors alias the dead conv temporaries) ----
    char* ws = (char*)d_ws;
    float*    scal = (float*)ws;                        // [0, 2 KiB)
    bf16*     wpk1 = (bf16*)(ws + 2048);                // 18 KiB
    bf16*     wpk2 = (bf16*)(ws + 2048 + 18432);
    bf16*     wpk3 = (bf16*)(ws + 2048 + 36864);
    unsigned* wvh  = (unsigned*)(ws + 65536);           // [64 KiB, 64 KiB + 4 MiB)
    char*     A    = ws + 65536 + (size_t)NB*PLANE*4;   // shared region, 136 MiB
    // conv-phase mapping of A:
    bf16*  tmp1 = (bf16*)(A);                                  // 64 MiB
    bf16*  tmp2 = (bf16*)(A + (size_t)NB*32*PLANE*2);          // 64 MiB
    float* dv   = (float*)(A + (size_t)NB*32*PLANE*4);         // 4 MiB
    float* dh   = (float*)(A + (size_t)NB*32*PLANE*4 + (size_t)NB*PLANE*4);
    // CG-phase mapping of A (tmp1/tmp2/dv/dh dead by then):
    float* pA  = (float*)(A);
    float* pB  = (float*)(A + (size_t)NB*PLANE*4);
    float* rA  = (float*)(A + (size_t)NB*PLANE*8);
    float* rB  = (float*)(A + (size_t)NB*PLANE*12);
    float* apA = (float*)(A + (size_t)NB*PLANE*16);
    float* apB = (float*)(A + (size_t)NB*PLANE*20);

    dim3 cgrid(16, 16, NB);

    // repack the three 32->32 conv weights into MFMA fragment layout
    wrepack3<<<108,256,0,stream>>>(gw2, sw2, vw2, wpk1, wpk2, wpk3);

    // feature branch g = conv(relu(conv(guide)))
    conv3x3_first<3,3,true><<<cgrid,256,0,stream>>>(guide, guide, gw1, gb1, tmp1);
    conv3x3_mfma<false><<<cgrid,256,0,stream>>>(tmp1, wpk1, gb2, tmp2);
    dvdh_cl<false><<<4096,256,0,stream>>>(tmp2, dv, dh);
    // feature branch s = conv(relu(conv(y_bicubic)))
    conv3x3_first<1,1,true><<<cgrid,256,0,stream>>>(ybic, ybic, sw1, sb1, tmp1);
    conv3x3_mfma<false><<<cgrid,256,0,stream>>>(tmp1, wpk2, sb2, tmp2);
    dvdh_cl<true><<<4096,256,0,stream>>>(tmp2, dv, dh);
    aff2_kernel<<<4096,256,0,stream>>>(dv, dh, llam, lmu, wvh, aff_out);
    // variance branch
    conv3x3_first<4,3,true><<<cgrid,256,0,stream>>>(guide, ybic, vw1, vb1, tmp1);
    conv3x3_mfma<true><<<cgrid,256,0,stream>>>(tmp1, wpk3, vb2, tmp2);
    conv3x3_last<<<4096,256,0,stream>>>(tmp2, vw3, vb3, var_out);

    // CG: init + first(Ap0) + 99 fused + tail   (one stencil dispatch per iteration)
    hipMemsetAsync(scal, 0, 2048, stream);
    cg_init<<<1024,256,0,stream>>>(wvh, mask, source, ybic, llam, x_out, rA, pA, scal);
    cg_fused<true><<<1024,256,0,stream>>>(wvh, mask, llam, rA, pA, apA,
                                          x_out, rB, pB, apA, scal, 0);
    for (int k = 1; k <= 99; k++) {
        float* ro  = (k & 1) ? rA : rB;   float* rn  = (k & 1) ? rB : rA;
        float* po  = (k & 1) ? pA : pB;   float* pn  = (k & 1) ? pB : pA;
        float* aoo = (k & 1) ? apA : apB; float* an  = (k & 1) ? apB : apA;
        cg_fused<false><<<1024,256,0,stream>>>(wvh, mask, llam, ro, po, aoo,
                                               x_out, rn, pn, an, scal, k);
    }
    // k=99 wrote the B set: p_99 = pB
    cg_lastx<<<1024,256,0,stream>>>(x_out, pB, scal);
}

// Round 13
// 2302.098 us; speedup vs baseline: 9.1757x; 1.2864x over previous
//
#include <hip/hip_runtime.h>
#include <hip/hip_bf16.h>

typedef __hip_bfloat16 bf16;
typedef __attribute__((ext_vector_type(8))) short short8;
typedef __attribute__((ext_vector_type(4))) float f32x4;

#define NB 16
#define PLANE (256*256)

static __device__ __forceinline__ short f2bf(float v){
    __hip_bfloat16 h = __float2bfloat16(v);
    short s; __builtin_memcpy(&s, &h, 2); return s;
}
static __device__ __forceinline__ float bf2f(short s){
    union { unsigned u; float f; } cv;
    cv.u = ((unsigned)(unsigned short)s) << 16; return cv.f;
}

// ---------------- first-layer conv 3x3 (small CIN, VALU), output channel-last bf16 ----------------
template<int CIN, int SPLIT, bool RELU>
__global__ __launch_bounds__(256)
void conv3x3_first(const float* __restrict__ in, const float* __restrict__ in2,
                   const float* __restrict__ wgt, const float* __restrict__ bias,
                   bf16* __restrict__ out)
{
    __shared__ float s_in[CIN][18][18];
    __shared__ float s_w[CIN*9*32];
    const int n  = blockIdx.z;
    const int ty0 = blockIdx.y * 16, tx0 = blockIdx.x * 16;
    const int tid = threadIdx.x;

    for (int idx = tid; idx < CIN*9*32; idx += 256) {
        int co = idx & 31; int rest = idx >> 5;     // rest = ci*9 + k
        s_w[idx] = wgt[(co*CIN + rest/9)*9 + rest%9];
    }
    for (int idx = tid; idx < CIN*18*18; idx += 256) {
        int ci = idx / (18*18); int rr = idx % (18*18);
        int yy = rr / 18, xx = rr % 18;
        int y = ty0 + yy - 1, x = tx0 + xx - 1;
        float v = 0.f;
        if (y >= 0 && y < 256 && x >= 0 && x < 256) {
            if (ci < SPLIT) v = in [((size_t)(n*SPLIT + ci)*256 + y)*256 + x];
            else            v = in2[((size_t)(n*(CIN-SPLIT) + (ci-SPLIT))*256 + y)*256 + x];
        }
        s_in[ci][yy][xx] = v;
    }
    __syncthreads();

    const int ty = tid >> 4, tx = tid & 15;
    float acc[32];
    #pragma unroll
    for (int co = 0; co < 32; co++) acc[co] = bias[co];

    #pragma unroll
    for (int ci = 0; ci < CIN; ci++) {
        #pragma unroll
        for (int ky = 0; ky < 3; ky++)
        #pragma unroll
        for (int kx = 0; kx < 3; kx++) {
            float v = s_in[ci][ty+ky][tx+kx];
            const float* wp = &s_w[(ci*9 + ky*3 + kx)*32];
            #pragma unroll
            for (int co = 0; co < 32; co++) acc[co] = fmaf(v, wp[co], acc[co]);
        }
    }
    const int y = ty0 + ty, x = tx0 + tx;
    size_t base = (((size_t)n*256 + y)*256 + x)*32;
    #pragma unroll
    for (int c = 0; c < 32; c += 8) {
        short8 vv;
        #pragma unroll
        for (int j = 0; j < 8; j++) {
            float v = acc[c+j];
            if (RELU) v = fmaxf(v, 0.f);
            vv[j] = f2bf(v);
        }
        *(short8*)((short*)out + base + c) = vv;
    }
}

// ---------------- weight repack for MFMA convs: [co][ci][tap] f32 -> [tap][co][ci] bf16 ----------------
__global__ __launch_bounds__(256)
void wrepack3(const float* __restrict__ a, const float* __restrict__ b,
              const float* __restrict__ c,
              bf16* __restrict__ oa, bf16* __restrict__ ob, bf16* __restrict__ oc)
{
    int j = blockIdx.x*256 + threadIdx.x;        // 0..27647
    if (j >= 3*9216) return;
    int set = j / 9216, r = j % 9216;
    int tap = r >> 10, rem = r & 1023, co = rem >> 5, ci = rem & 31;
    const float* src = (set == 0) ? a : (set == 1) ? b : c;
    bf16* dst = (set == 0) ? oa : (set == 1) ? ob : oc;
    dst[r] = __float2bfloat16(src[(co*32 + ci)*9 + tap]);
}

// ---------------- heavy conv 3x3 (32->32) via MFMA, channel-last bf16 in/out ----------------
template<bool RELU>
__global__ __launch_bounds__(256)
void conv3x3_mfma(const bf16* __restrict__ in, const bf16* __restrict__ wpk,
                  const float* __restrict__ bias, bf16* __restrict__ out)
{
    const int lane = threadIdx.x & 63, wid = threadIdx.x >> 6;
    const int m = lane & 15, quad = lane >> 4, k0 = quad*8;
    const int n  = blockIdx.z;
    const int x0 = blockIdx.x * 16;
    const int y0 = blockIdx.y * 16 + wid * 4;

    const short* wp = (const short*)wpk;
    short8 bw[2][9];
    #pragma unroll
    for (int g = 0; g < 2; g++)
        #pragma unroll
        for (int tap = 0; tap < 9; tap++)
            bw[g][tap] = *(const short8*)(wp + ((tap*32 + g*16 + m)*32 + k0));
    const float b0 = bias[m], b1 = bias[16 + m];

    const short* inp = (const short*)in + (size_t)n*PLANE*32;
    short* outp = (short*)out + (size_t)n*PLANE*32;

    #pragma unroll
    for (int r = 0; r < 4; r++) {
        const int y = y0 + r;
        f32x4 acc0 = { b0, b0, b0, b0 };
        f32x4 acc1 = { b1, b1, b1, b1 };
        #pragma unroll
        for (int ky = 0; ky < 3; ky++) {
            const int yy = y + ky - 1;
            const bool yok = (unsigned)yy < 256u;
            #pragma unroll
            for (int kx = 0; kx < 3; kx++) {
                const int xp = x0 + kx - 1 + m;
                short8 a = { 0,0,0,0,0,0,0,0 };
                if (yok && (unsigned)xp < 256u)
                    a = *(const short8*)(inp + ((size_t)yy*256 + xp)*32 + k0);
                acc0 = __builtin_amdgcn_mfma_f32_16x16x32_bf16(a, bw[0][ky*3+kx], acc0, 0, 0, 0);
                acc1 = __builtin_amdgcn_mfma_f32_16x16x32_bf16(a, bw[1][ky*3+kx], acc1, 0, 0, 0);
            }
        }
        #pragma unroll
        for (int reg = 0; reg < 4; reg++) {
            int px = x0 + quad*4 + reg;
            size_t idx = ((size_t)y*256 + px)*32;
            float v0 = acc0[reg], v1 = acc1[reg];
            if (RELU) { v0 = fmaxf(v0, 0.f); v1 = fmaxf(v1, 0.f); }
            outp[idx + m]      = f2bf(v0);
            outp[idx + 16 + m] = f2bf(v1);
        }
    }
}

// ---------------- final conv 3x3 (32->1), channel-last input ----------------
__global__ __launch_bounds__(256)
void conv3x3_last(const bf16* __restrict__ in, const float* __restrict__ wgt,
                  const float* __restrict__ bias, float* __restrict__ out)
{
    __shared__ float s_w[288];
    int tid = threadIdx.x;
    for (int i = tid; i < 288; i += 256) s_w[i] = wgt[i];
    __syncthreads();
    int gid = blockIdx.x*256 + tid;
    int n = gid >> 16, h = (gid >> 8) & 255, w = gid & 255;
    const short* inp = (const short*)in + (size_t)n*PLANE*32;
    float sum = bias[0];
    #pragma unroll
    for (int ky = 0; ky < 3; ky++) {
        int yy = h + ky - 1;
        if ((unsigned)yy >= 256u) continue;
        #pragma unroll
        for (int kx = 0; kx < 3; kx++) {
            int xx = w + kx - 1;
            if ((unsigned)xx >= 256u) continue;
            const short8* pp = (const short8*)(inp + ((size_t)yy*256 + xx)*32);
            int tap = ky*3 + kx;
            #pragma unroll
            for (int c4 = 0; c4 < 4; c4++) {
                short8 v = pp[c4];
                #pragma unroll
                for (int j = 0; j < 8; j++)
                    sum = fmaf(bf2f(v[j]), s_w[(c4*8+j)*9 + tap], sum);
            }
        }
    }
    out[gid] = sum;
}

// ---------------- squared neighbor diffs over 32 channels, channel-last ----------------
template<bool ACCUM>
__global__ __launch_bounds__(256)
void dvdh_cl(const bf16* __restrict__ f, float* __restrict__ dv, float* __restrict__ dh)
{
    int bid = blockIdx.x;
    int n = bid >> 8, i = bid & 255, j = threadIdx.x;
    const short8* pc = (const short8*)((const short*)f + (((size_t)n*256 + i)*256 + j)*32);
    const short8* pr = (j < 255) ? pc + 4    : pc;
    const short8* pd = (i < 255) ? pc + 1024 : pc;
    float adv = 0.f, adh = 0.f;
    #pragma unroll
    for (int c4 = 0; c4 < 4; c4++) {
        short8 sc = pc[c4], sr = pr[c4], sd = pd[c4];
        #pragma unroll
        for (int e = 0; e < 8; e++) {
            float fc = bf2f(sc[e]);
            float d1 = bf2f(sr[e]) - fc;
            float d2 = bf2f(sd[e]) - fc;
            adh = fmaf(d1, d1, adh);
            adv = fmaf(d2, d2, adv);
        }
    }
    int o = (n*256 + i)*256 + j;
    if (ACCUM) { dv[o] += adv; dh[o] += adh; }
    else       { dv[o]  = adv; dh[o]  = adh; }
}

// ---------------- affinity: packed bf16 (wv,wh) for CG + 5-plane fp32 output ----------------
__global__ __launch_bounds__(256)
void aff2_kernel(const float* __restrict__ dv, const float* __restrict__ dh,
                 const float* __restrict__ llam, const float* __restrict__ lmu,
                 unsigned* __restrict__ wvh, float* __restrict__ aff)
{
    int bid = blockIdx.x;
    int n = bid >> 8, h = bid & 255, w = threadIdx.x;
    float mu = expf(lmu[0]), lam = expf(llam[0]);
    int rb = (n*256 + h)*256 + w;
    float wvv = (h < 255) ? expf(-mu * dv[rb]) : 0.f;
    float whv = (w < 255) ? expf(-mu * dh[rb]) : 0.f;
    unsigned pv = (unsigned)(unsigned short)f2bf(wvv);
    unsigned ph = (unsigned)(unsigned short)f2bf(whv);
    wvh[rb] = pv | (ph << 16);
    float w_up = (h > 0) ? expf(-mu * dv[rb - 256]) : 0.f;
    float w_lf = (w > 0) ? expf(-mu * dh[rb - 1])   : 0.f;
    float ctr  = w_up + wvv + w_lf + whv + lam;
    float* a = aff + ((size_t)n*5)*PLANE + h*256 + w;
    a[0]        = w_up;
    a[PLANE]    = wvv;
    a[2*PLANE]  = w_lf;
    a[3*PLANE]  = whv;
    a[4*PLANE]  = ctr;
}

// ---------------- shared reduction ----------------
static __device__ __forceinline__ void block_reduce_atomic(float v, float* dst, float* sh)
{
    #pragma unroll
    for (int o = 32; o > 0; o >>= 1) v += __shfl_down(v, o, 64);
    __syncthreads();
    if ((threadIdx.x & 63) == 0) sh[threadIdx.x >> 6] = v;
    __syncthreads();
    if (threadIdx.x == 0) atomicAdd(dst, sh[0]+sh[1]+sh[2]+sh[3]);
}

// ============ CG: 512 blocks x 64x32 tile, 8 px/thread, fp32 vectors ============
// scal: gamma_real[k]=scal[k] (0..100), pAp[k]=scal[128+k], ApAp[k]=scal[256+k]
// Thread (tx=tid&31, tyb=tid>>5) owns rows tyo+tyb+8i (i=0..7), col txo+tx.
// 8x8 avgpool blocks nest in tile: s_bs[32] = 8 brows x 4 bcols, lb = i*4 + (tx>>3).
// Stencil weights prefetched at kernel top (0-sentinel at borders; bf2f(0)=0).

__global__ __launch_bounds__(256)
void cg_init(const unsigned* __restrict__ wvh,
             const float* __restrict__ mask, const float* __restrict__ src,
             const float* __restrict__ ybic, const float* __restrict__ llam,
             float* __restrict__ x, float* __restrict__ r, float* __restrict__ p0,
             float* __restrict__ scal)
{
    __shared__ float s_pn[66][34];
    __shared__ float s_part[256], s_bs[32], s_red[4];
    const int tid = threadIdx.x;
    const int b = blockIdx.x;
    const int n = b >> 5, t = b & 31;
    const int tyo = (t >> 3) * 64, txo = (t & 7) * 32;
    const int tx = tid & 31, tyb = tid >> 5;
    const int w = txo + tx;
    const float lam = expf(llam[0]);

    const unsigned* wn = wvh + (size_t)n*PLANE;
    const float* ybn = ybic + (size_t)n*PLANE;

    int hh[8], idx[8];
    unsigned wc[8], wu[8], wl[8];
    #pragma unroll
    for (int i = 0; i < 8; i++) {
        hh[i]  = tyo + tyb + 8*i;
        idx[i] = hh[i]*256 + w;
        wc[i] = wn[idx[i]];
        wu[i] = (hh[i] > 0) ? wn[idx[i]-256] : 0u;
        wl[i] = (w > 0)     ? wn[idx[i]-1]   : 0u;
    }
    float yv[8];
    #pragma unroll
    for (int i = 0; i < 8; i++) {
        yv[i] = ybn[idx[i]];
        s_pn[1 + tyb + 8*i][1 + tx] = yv[i];
    }
    if (tid < 192) {
        int y, xx;
        if      (tid < 32)  { y = tyo - 1;            xx = txo + tid;       }
        else if (tid < 64)  { y = tyo + 64;           xx = txo + (tid-32);  }
        else if (tid < 128) { y = tyo + (tid-64);     xx = txo - 1;         }
        else                { y = tyo + (tid-128);    xx = txo + 32;        }
        float v = 0.f;
        if (y >= 0 && y < 256 && xx >= 0 && xx < 256) v = ybn[y*256 + xx];
        s_pn[y - tyo + 1][xx - txo + 1] = v;
    }
    __syncthreads();
    {
        int segrow = tid >> 2, segcol = tid & 3;
        const float* rw = &s_pn[1 + segrow][1 + segcol*8];
        s_part[tid] = rw[0]+rw[1]+rw[2]+rw[3]+rw[4]+rw[5]+rw[6]+rw[7];
    }
    __syncthreads();
    if (tid < 32) {
        int brow = tid >> 2, bcol = tid & 3;
        float s = 0.f;
        #pragma unroll
        for (int rr = 0; rr < 8; rr++) s += s_part[(brow*8 + rr)*4 + bcol];
        s_bs[tid] = s;
    }
    __syncthreads();

    float* rn = r  + (size_t)n*PLANE;
    float* pn = p0 + (size_t)n*PLANE;
    float* xn = x  + (size_t)n*PLANE;
    float g0 = 0.f;
    #pragma unroll
    for (int i = 0; i < 8; i++) {
        int yy = 1 + tyb + 8*i, xx = 1 + tx;
        float wvd = bf2f((short)(wc[i] & 0xffff));
        float whr = bf2f((short)(wc[i] >> 16));
        float wvu = bf2f((short)(wu[i] & 0xffff));
        float whl = bf2f((short)(wl[i] >> 16));
        float s = wvu*s_pn[yy-1][xx] + wvd*s_pn[yy+1][xx]
                + whl*s_pn[yy][xx-1] + whr*s_pn[yy][xx+1];
        float deg = wvu+wvd+whl+whr;
        int bi = n*1024 + (hh[i]>>3)*32 + (w>>3);
        float mv = mask[bi];
        float ax = deg*s_pn[yy][xx] - s + lam*mv*(1.f/4096.f)*s_bs[i*4 + (tx>>3)];
        float brhs = lam*mv*src[bi]*(1.f/64.f);
        float r0 = brhs - ax;
        rn[idx[i]] = r0; pn[idx[i]] = r0; xn[idx[i]] = yv[i];
        g0 += r0*r0;
    }
    block_reduce_atomic(g0, &scal[0], s_red);
}

// fused iteration k (non-FIRST): alpha = g[k-1]/pAp[k-1] (real);
// beta = (alpha^2*ApAp[k-1] - g[k-1]) / g[k-1] (one-step recurrence);
// r_new = r - alpha*Ap; x += alpha*p; p_new = r_new + beta*p;
// Ap_new = A p_new; reduce pAp[k], ApAp[k], g_real[k].
// FIRST (k=0): no updates; Ap_0 = A p_0; reduce pAp[0], ApAp[0].
template<bool FIRST>
__global__ __launch_bounds__(256)
void cg_fused(const unsigned* __restrict__ wvh, const float* __restrict__ mask,
              const float* __restrict__ llam,
              const float* __restrict__ r_old, const float* __restrict__ p_old,
              const float* __restrict__ Ap_old, float* __restrict__ x,
              float* __restrict__ r_new, float* __restrict__ p_new,
              float* __restrict__ Ap_new, float* __restrict__ scal, int k)
{
    __shared__ float s_pn[66][34];
    __shared__ float s_part[256], s_bs[32], s_red[4];
    const int tid = threadIdx.x;
    const int b = blockIdx.x;
    const int n = b >> 5, t = b & 31;
    const int tyo = (t >> 3) * 64, txo = (t & 7) * 32;
    const int tx = tid & 31, tyb = tid >> 5;
    const int w = txo + tx;
    const float lam = expf(llam[0]);

    float alpha = 0.f, beta = 0.f;
    if (!FIRST) {
        float gprev = scal[k-1], pap = scal[128+k-1], apap = scal[256+k-1];
        alpha = gprev / pap;
        beta = (alpha*alpha*apap - gprev) / gprev;
    }

    const unsigned* wn = wvh + (size_t)n*PLANE;
    const float* ro = r_old  + (size_t)n*PLANE;
    const float* po = p_old  + (size_t)n*PLANE;
    const float* ao = Ap_old + (size_t)n*PLANE;
    float* xn  = x      + (size_t)n*PLANE;
    float* rw  = r_new  + (size_t)n*PLANE;
    float* pw  = p_new  + (size_t)n*PLANE;
    float* apw = Ap_new + (size_t)n*PLANE;

    // prefetch stencil weights (independent of phase 1 — overlaps latency)
    int hh[8], idx[8];
    unsigned wc[8], wu[8], wl[8];
    #pragma unroll
    for (int i = 0; i < 8; i++) {
        hh[i]  = tyo + tyb + 8*i;
        idx[i] = hh[i]*256 + w;
        wc[i] = wn[idx[i]];
        wu[i] = (hh[i] > 0) ? wn[idx[i]-256] : 0u;
        wl[i] = (w > 0)     ? wn[idx[i]-1]   : 0u;
    }

    float pv[8], gsum = 0.f;
    #pragma unroll
    for (int i = 0; i < 8; i++) {
        float pO = po[idx[i]];
        float pN;
        if (FIRST) {
            pN = pO;
        } else {
            float rN = fmaf(-alpha, ao[idx[i]], ro[idx[i]]);
            xn[idx[i]] = fmaf(alpha, pO, xn[idx[i]]);
            pN = fmaf(beta, pO, rN);
            rw[idx[i]] = rN;
            pw[idx[i]] = pN;
            gsum += rN*rN;
        }
        pv[i] = pN;
        s_pn[1 + tyb + 8*i][1 + tx] = pN;
    }
    if (tid < 192) {
        int y, xx;
        if      (tid < 32)  { y = tyo - 1;            xx = txo + tid;       }
        else if (tid < 64)  { y = tyo + 64;           xx = txo + (tid-32);  }
        else if (tid < 128) { y = tyo + (tid-64);     xx = txo - 1;         }
        else                { y = tyo + (tid-128);    xx = txo + 32;        }
        float v = 0.f;
        if (y >= 0 && y < 256 && xx >= 0 && xx < 256) {
            int id2 = y*256 + xx;
            if (FIRST) v = po[id2];
            else       v = fmaf(beta, po[id2], fmaf(-alpha, ao[id2], ro[id2]));
        }
        s_pn[y - tyo + 1][xx - txo + 1] = v;
    }
    __syncthreads();
    {
        int segrow = tid >> 2, segcol = tid & 3;
        const float* rr = &s_pn[1 + segrow][1 + segcol*8];
        s_part[tid] = rr[0]+rr[1]+rr[2]+rr[3]+rr[4]+rr[5]+rr[6]+rr[7];
    }
    __syncthreads();
    if (tid < 32) {
        int brow = tid >> 2, bcol = tid & 3;
        float s = 0.f;
        #pragma unroll
        for (int rr = 0; rr < 8; rr++) s += s_part[(brow*8 + rr)*4 + bcol];
        s_bs[tid] = s;
    }
    __syncthreads();

    float papsum = 0.f, apapsum = 0.f;
    #pragma unroll
    for (int i = 0; i < 8; i++) {
        int yy = 1 + tyb + 8*i, xx = 1 + tx;
        float wvd = bf2f((short)(wc[i] & 0xffff));
        float whr = bf2f((short)(wc[i] >> 16));
        float wvu = bf2f((short)(wu[i] & 0xffff));
        float whl = bf2f((short)(wl[i] >> 16));
        float s = wvu*s_pn[yy-1][xx] + wvd*s_pn[yy+1][xx]
                + whl*s_pn[yy][xx-1] + whr*s_pn[yy][xx+1];
        float deg = wvu+wvd+whl+whr;
        int bi = n*1024 + (hh[i]>>3)*32 + (w>>3);
        float c1 = lam*mask[bi]*(1.f/4096.f);
        float ap = deg*s_pn[yy][xx] - s + c1*s_bs[i*4 + (tx>>3)];
        apw[idx[i]] = ap;
        papsum  += pv[i]*ap;
        apapsum += ap*ap;
    }
    block_reduce_atomic(papsum,  &scal[128+k], s_red);
    block_reduce_atomic(apapsum, &scal[256+k], s_red);
    if (!FIRST) block_reduce_atomic(gsum, &scal[k], s_red);
}

// tail: x += alpha_99 * p_99
__global__ __launch_bounds__(256)
void cg_lastx(float* __restrict__ x, const float* __restrict__ p,
              const float* __restrict__ scal)
{
    int g = blockIdx.x*256 + threadIdx.x;
    float alpha = scal[99] / scal[128+99];
    float4 pv = ((const float4*)p)[g];
    float4 xv = ((float4*)x)[g];
    xv.x = fmaf(alpha, pv.x, xv.x);
    xv.y = fmaf(alpha, pv.y, xv.y);
    xv.z = fmaf(alpha, pv.z, xv.z);
    xv.w = fmaf(alpha, pv.w, xv.w);
    ((float4*)x)[g] = xv;
}

// ---------------- host ----------------
extern "C" void kernel_launch(void* const* d_in, const int* in_sizes, int n_in,
                              void* d_out, int out_size, void* d_ws, size_t ws_size,
                              hipStream_t stream)
{
    (void)in_sizes; (void)n_in; (void)out_size; (void)ws_size;
    const float* guide = (const float*)d_in[0];
    const float* source= (const float*)d_in[1];
    const float* mask  = (const float*)d_in[2];
    const float* ybic  = (const float*)d_in[3];
    const float* gw1 = (const float*)d_in[4];  const float* gb1 = (const float*)d_in[5];
    const float* gw2 = (const float*)d_in[6];  const float* gb2 = (const float*)d_in[7];
    const float* sw1 = (const float*)d_in[8];  const float* sb1 = (const float*)d_in[9];
    const float* sw2 = (const float*)d_in[10]; const float* sb2 = (const float*)d_in[11];
    const float* vw1 = (const float*)d_in[12]; const float* vb1 = (const float*)d_in[13];
    const float* vw2 = (const float*)d_in[14]; const float* vb2 = (const float*)d_in[15];
    const float* vw3 = (const float*)d_in[16]; const float* vb3 = (const float*)d_in[17];
    const float* llam = (const float*)d_in[18];
    const float* lmu  = (const float*)d_in[19];

    float* out     = (float*)d_out;
    float* x_out   = out;                 // y_pred (16,1,256,256)
    float* var_out = out + 1048576;       // var
    float* aff_out = out + 2097152;       // aff (16,5,256,256)

    // ---- workspace layout (~140.1 MiB; small persistent objects FIRST;
    //      CG vectors alias the dead conv temporaries) ----
    char* ws = (char*)d_ws;
    float*    scal = (float*)ws;                        // [0, 2 KiB)
    bf16*     wpk1 = (bf16*)(ws + 2048);                // 18 KiB
    bf16*     wpk2 = (bf16*)(ws + 2048 + 18432);
    bf16*     wpk3 = (bf16*)(ws + 2048 + 36864);
    unsigned* wvh  = (unsigned*)(ws + 65536);           // [64 KiB, 64 KiB + 4 MiB)
    char*     A    = ws + 65536 + (size_t)NB*PLANE*4;   // shared region, 136 MiB
    // conv-phase mapping of A:
    bf16*  tmp1 = (bf16*)(A);                                  // 64 MiB
    bf16*  tmp2 = (bf16*)(A + (size_t)NB*32*PLANE*2);          // 64 MiB
    float* dv   = (float*)(A + (size_t)NB*32*PLANE*4);         // 4 MiB
    float* dh   = (float*)(A + (size_t)NB*32*PLANE*4 + (size_t)NB*PLANE*4);
    // CG-phase mapping of A (tmp1/tmp2/dv/dh dead by then):
    float* pA  = (float*)(A);
    float* pB  = (float*)(A + (size_t)NB*PLANE*4);
    float* rA  = (float*)(A + (size_t)NB*PLANE*8);
    float* rB  = (float*)(A + (size_t)NB*PLANE*12);
    float* apA = (float*)(A + (size_t)NB*PLANE*16);
    float* apB = (float*)(A + (size_t)NB*PLANE*20);

    dim3 cgrid(16, 16, NB);

    // repack the three 32->32 conv weights into MFMA fragment layout
    wrepack3<<<108,256,0,stream>>>(gw2, sw2, vw2, wpk1, wpk2, wpk3);

    // feature branch g = conv(relu(conv(guide)))
    conv3x3_first<3,3,true><<<cgrid,256,0,stream>>>(guide, guide, gw1, gb1, tmp1);
    conv3x3_mfma<false><<<cgrid,256,0,stream>>>(tmp1, wpk1, gb2, tmp2);
    dvdh_cl<false><<<4096,256,0,stream>>>(tmp2, dv, dh);
    // feature branch s = conv(relu(conv(y_bicubic)))
    conv3x3_first<1,1,true><<<cgrid,256,0,stream>>>(ybic, ybic, sw1, sb1, tmp1);
    conv3x3_mfma<false><<<cgrid,256,0,stream>>>(tmp1, wpk2, sb2, tmp2);
    dvdh_cl<true><<<4096,256,0,stream>>>(tmp2, dv, dh);
    aff2_kernel<<<4096,256,0,stream>>>(dv, dh, llam, lmu, wvh, aff_out);
    // variance branch
    conv3x3_first<4,3,true><<<cgrid,256,0,stream>>>(guide, ybic, vw1, vb1, tmp1);
    conv3x3_mfma<true><<<cgrid,256,0,stream>>>(tmp1, wpk3, vb2, tmp2);
    conv3x3_last<<<4096,256,0,stream>>>(tmp2, vw3, vb3, var_out);

    // CG: init + first(Ap0) + 99 fused + tail   (one stencil dispatch per iteration)
    hipMemsetAsync(scal, 0, 2048, stream);
    cg_init<<<512,256,0,stream>>>(wvh, mask, source, ybic, llam, x_out, rA, pA, scal);
    cg_fused<true><<<512,256,0,stream>>>(wvh, mask, llam, rA, pA, apA,
                                         x_out, rB, pB, apA, scal, 0);
    for (int k = 1; k <= 99; k++) {
        float* ro  = (k & 1) ? rA : rB;   float* rn  = (k & 1) ? rB : rA;
        float* po  = (k & 1) ? pA : pB;   float* pn  = (k & 1) ? pB : pA;
        float* aoo = (k & 1) ? apA : apB; float* an  = (k & 1) ? apB : apA;
        cg_fused<false><<<512,256,0,stream>>>(wvh, mask, llam, ro, po, aoo,
                                              x_out, rn, pn, an, scal, k);
    }
    // k=99 wrote the B set: p_99 = pB
    cg_lastx<<<1024,256,0,stream>>>(x_out, pB, scal);
}